// Round 1
// baseline (926.069 us; speedup 1.0000x reference)
//
#include <hip/hip_runtime.h>

#define N_NODES 100000
#define N_EDGES 1600000
#define IN_F 3
#define HID 150
#define OUTF 64

// ---------------- kernels ----------------

// Per edge: deg[dst] += 1; agg1[dst][0..2] += x[src][0..2]
__global__ void k_edge_agg1(const int* __restrict__ src, const int* __restrict__ dst,
                            const float* __restrict__ x,
                            float* __restrict__ deg, float* __restrict__ agg1) {
    int e = blockIdx.x * blockDim.x + threadIdx.x;
    if (e >= N_EDGES) return;
    int s = src[e];
    int d = dst[e];
    atomicAdd(&deg[d], 1.0f);
    float x0 = x[s * 3 + 0];
    float x1 = x[s * 3 + 1];
    float x2 = x[s * 3 + 2];
    atomicAdd(&agg1[d * 3 + 0], x0);
    atomicAdd(&agg1[d * 3 + 1], x1);
    atomicAdd(&agg1[d * 3 + 2], x2);
}

// deg -> 1/max(deg,1), in place
__global__ void k_invdeg(float* __restrict__ deg) {
    int n = blockIdx.x * blockDim.x + threadIdx.x;
    if (n < N_NODES) deg[n] = 1.0f / fmaxf(deg[n], 1.0f);
}

// h[n][j] = relu( sum_k x[n][k]*W1s[k][j] + (agg1[n][k]*invd[n])*W1n[k][j] + b1[j] )
// one thread per (n, j); j = idx % 150
__global__ void k_layer1(const float* __restrict__ x, const float* __restrict__ agg1,
                         const float* __restrict__ invd,
                         const float* __restrict__ W1s, const float* __restrict__ W1n,
                         const float* __restrict__ b1, float* __restrict__ h) {
    int idx = blockIdx.x * blockDim.x + threadIdx.x;
    if (idx >= N_NODES * HID) return;
    int n = idx / HID;
    int j = idx - n * HID;
    float id = invd[n];
    float acc = b1[j];
    #pragma unroll
    for (int k = 0; k < IN_F; ++k) {
        float xs = x[n * 3 + k];
        float xn = agg1[n * 3 + k] * id;
        acc += xs * W1s[k * HID + j] + xn * W1n[k * HID + j];
    }
    h[idx] = fmaxf(acc, 0.0f);
}

// per node (64 lanes = one output column each):
//   out[n][j] = b2[j] + sum_k h[n][k] * W2s[k][j]
//   p  [n][j] =         sum_k h[n][k] * W2n[k][j]
// 4 nodes per 256-thread block; h rows staged in LDS.
__global__ void k_layer2(const float* __restrict__ h,
                         const float* __restrict__ W2s, const float* __restrict__ W2n,
                         const float* __restrict__ b2,
                         float* __restrict__ out, float* __restrict__ p) {
    __shared__ float sh[4][HID];
    int node0 = blockIdx.x * 4;
    for (int t = threadIdx.x; t < 4 * HID; t += 256) {
        int r = t / HID;
        int c = t - r * HID;
        int n = node0 + r;
        sh[r][c] = (n < N_NODES) ? h[n * HID + c] : 0.0f;
    }
    __syncthreads();
    int r = threadIdx.x >> 6;
    int j = threadIdx.x & 63;
    int n = node0 + r;
    if (n >= N_NODES) return;
    float accS = b2[j];
    float accN = 0.0f;
    for (int k = 0; k < HID; ++k) {
        float hv = sh[r][k];
        accS += hv * W2s[k * OUTF + j];
        accN += hv * W2n[k * OUTF + j];
    }
    out[n * OUTF + j] = accS;
    p[n * OUTF + j]   = accN;
}

// per edge, 64 lanes: out[dst][lane] += p[src][lane] * invd[dst]
// 4 edges per 256-thread block
__global__ void k_edge_agg2(const int* __restrict__ src, const int* __restrict__ dst,
                            const float* __restrict__ p, const float* __restrict__ invd,
                            float* __restrict__ out) {
    int e = blockIdx.x * 4 + (threadIdx.x >> 6);
    if (e >= N_EDGES) return;
    int lane = threadIdx.x & 63;
    int s = src[e];
    int d = dst[e];
    float v = p[s * OUTF + lane] * invd[d];
    atomicAdd(&out[d * OUTF + lane], v);
}

// ---------------- launcher ----------------

extern "C" void kernel_launch(void* const* d_in, const int* in_sizes, int n_in,
                              void* d_out, int out_size, void* d_ws, size_t ws_size,
                              hipStream_t stream) {
    const float* x   = (const float*)d_in[0];
    const int*   src = (const int*)d_in[1];
    const int*   dst = (const int*)d_in[2];
    const float* W1s = (const float*)d_in[3];
    const float* W1n = (const float*)d_in[4];
    const float* b1  = (const float*)d_in[5];
    const float* W2s = (const float*)d_in[6];
    const float* W2n = (const float*)d_in[7];
    const float* b2  = (const float*)d_in[8];
    float* out = (float*)d_out;

    // workspace layout (floats), 256B-aligned offsets
    char* ws = (char*)d_ws;
    float* deg  = (float*)(ws);                           // N floats          (0.4 MB)
    float* agg1 = (float*)(ws + ((size_t)N_NODES * 4 + 255) / 256 * 256);            // 3N floats (1.2 MB)
    size_t off_h = (((size_t)N_NODES * 4 + 255) / 256 * 256) + (((size_t)N_NODES * 3 * 4 + 255) / 256 * 256);
    float* h = (float*)(ws + off_h);                      // N*150 floats      (60 MB)
    size_t off_p = off_h + (((size_t)N_NODES * HID * 4 + 255) / 256 * 256);
    float* p = (float*)(ws + off_p);                      // N*64 floats       (25.6 MB)

    // zero deg + agg1 (contiguous-ish: two memsets to be safe w/ alignment)
    hipMemsetAsync(deg, 0, (size_t)N_NODES * 4, stream);
    hipMemsetAsync(agg1, 0, (size_t)N_NODES * 3 * 4, stream);

    {   // edge aggregation for layer 1
        int threads = 256;
        int blocks = (N_EDGES + threads - 1) / threads;
        k_edge_agg1<<<blocks, threads, 0, stream>>>(src, dst, x, deg, agg1);
    }
    {   // invert degree
        int threads = 256;
        int blocks = (N_NODES + threads - 1) / threads;
        k_invdeg<<<blocks, threads, 0, stream>>>(deg);
    }
    {   // layer 1 dense
        int total = N_NODES * HID;
        int threads = 256;
        int blocks = (total + threads - 1) / threads;
        k_layer1<<<blocks, threads, 0, stream>>>(x, agg1, deg, W1s, W1n, b1, h);
    }
    {   // layer 2 dense: out_self and p
        int blocks = (N_NODES + 3) / 4;
        k_layer2<<<blocks, 256, 0, stream>>>(h, W2s, W2n, b2, out, p);
    }
    {   // edge aggregation for layer 2 (adds into out)
        int blocks = (N_EDGES + 3) / 4;
        k_edge_agg2<<<blocks, 256, 0, stream>>>(src, dst, p, deg, out);
    }
}

// Round 2
// 759.584 us; speedup vs baseline: 1.2192x; 1.2192x over previous
//
#include <hip/hip_runtime.h>

#define N_NODES 100000
#define N_EDGES 1600000
#define HID 150
#define OUTF 64

// ---------------- CSR build ----------------

__global__ void k_hist(const int* __restrict__ dst, int* __restrict__ degi) {
    int e = blockIdx.x * blockDim.x + threadIdx.x;
    if (e < N_EDGES) atomicAdd(&degi[dst[e]], 1);
}

// single block, 1024 threads: exclusive scan of degi -> row_start, cursor; invd
__global__ __launch_bounds__(1024) void k_scan(const int* __restrict__ degi,
                                               int* __restrict__ row_start,
                                               int* __restrict__ cursor,
                                               float* __restrict__ invd) {
    __shared__ int part[1024];
    int tid = threadIdx.x;
    const int CH = (N_NODES + 1023) / 1024;  // 98
    int b = tid * CH;
    int e = min(b + CH, N_NODES);
    if (b > N_NODES) b = N_NODES;
    int s = 0;
    for (int i = b; i < e; ++i) s += degi[i];
    part[tid] = s;
    __syncthreads();
    // Hillis-Steele inclusive scan
    for (int off = 1; off < 1024; off <<= 1) {
        int v = part[tid];
        int vp = (tid >= off) ? part[tid - off] : 0;
        __syncthreads();
        part[tid] = v + vp;
        __syncthreads();
    }
    int run = (tid > 0) ? part[tid - 1] : 0;
    for (int i = b; i < e; ++i) {
        int d = degi[i];
        row_start[i] = run;
        cursor[i] = run;
        invd[i] = 1.0f / fmaxf((float)d, 1.0f);
        run += d;
    }
    if (tid == 1023) row_start[N_NODES] = part[1023];
}

__global__ void k_scatter(const int* __restrict__ src, const int* __restrict__ dst,
                          int* __restrict__ cursor, int* __restrict__ csr_src) {
    int e = blockIdx.x * blockDim.x + threadIdx.x;
    if (e >= N_EDGES) return;
    int idx = atomicAdd(&cursor[dst[e]], 1);
    csr_src[idx] = src[e];
}

// ---------------- layer-1 neighbor mean (pull, 3 feats) ----------------

__global__ void k_agg1(const int* __restrict__ row_start, const int* __restrict__ csr_src,
                       const float* __restrict__ x, const float* __restrict__ invd,
                       float* __restrict__ hn) {
    int n = blockIdx.x * blockDim.x + threadIdx.x;
    if (n >= N_NODES) return;
    int b = row_start[n], e = row_start[n + 1];
    float s0 = 0.f, s1 = 0.f, s2 = 0.f;
    for (int i = b; i < e; ++i) {
        int s = csr_src[i];
        s0 += x[s * 3 + 0];
        s1 += x[s * 3 + 1];
        s2 += x[s * 3 + 2];
    }
    float id = invd[n];
    hn[n * 3 + 0] = s0 * id;
    hn[n * 3 + 1] = s1 * id;
    hn[n * 3 + 2] = s2 * id;
}

// ---------------- W2 interleave: W2c[k][0..63]=W2s, [64..127]=W2n ----------------

__global__ void k_prep_w2(const float* __restrict__ W2s, const float* __restrict__ W2n,
                          float* __restrict__ W2c) {
    int idx = blockIdx.x * blockDim.x + threadIdx.x;
    if (idx >= HID * 128) return;
    int k = idx >> 7, j = idx & 127;
    W2c[idx] = (j < 64) ? W2s[k * 64 + j] : W2n[k * 64 + (j - 64)];
}

// ---------------- fused layer1 + layer2 GEMM ----------------
// grid.x = node tiles of 64, grid.y = 2 (0: self half -> out (+b2), 1: neigh half -> p)
// block 256 = 16 (node groups) x 16 (col groups), thread tile 4 nodes x 4 cols
__global__ __launch_bounds__(256, 2) void k_gemm(
        const float* __restrict__ x, const float* __restrict__ hn,
        const float* __restrict__ W1s, const float* __restrict__ W1n,
        const float* __restrict__ b1, const float* __restrict__ W2c,
        const float* __restrict__ b2,
        float* __restrict__ out, float* __restrict__ p) {
    __shared__ float shT[HID][64];   // h transposed: shT[k][n]   38.4 KB
    __shared__ float sW2[HID][64];   // W2 half tile: sW2[k][c]   38.4 KB
    const int half = blockIdx.y;
    const int n0 = blockIdx.x * 64;
    const int tid = threadIdx.x;

    // stage W2 half tile (coalesced global read, stride-1 LDS write)
    for (int idx = tid; idx < HID * 64; idx += 256) {
        int k = idx >> 6, c = idx & 63;
        sW2[k][c] = W2c[k * 128 + half * 64 + c];
    }
    // fused layer1: compute h tile directly into LDS (transposed)
    for (int idx = tid; idx < HID * 64; idx += 256) {
        int k = idx >> 6, n = idx & 63;
        int node = n0 + n;
        float h = 0.0f;
        if (node < N_NODES) {
            h = b1[k];
            #pragma unroll
            for (int i = 0; i < 3; ++i) {
                h += x[node * 3 + i] * W1s[i * HID + k]
                   + hn[node * 3 + i] * W1n[i * HID + k];
            }
            h = fmaxf(h, 0.0f);
        }
        shT[k][n] = h;
    }
    __syncthreads();

    const int tc = tid & 15;   // col group: cols tc*4 .. +3
    const int tn = tid >> 4;   // node group: nodes tn*4 .. +3
    float acc[4][4];
    #pragma unroll
    for (int i = 0; i < 4; ++i)
        #pragma unroll
        for (int q = 0; q < 4; ++q) acc[i][q] = 0.0f;

    #pragma unroll 2
    for (int k = 0; k < HID; ++k) {
        float4 a4 = *(const float4*)&shT[k][tn * 4];
        float4 b4 = *(const float4*)&sW2[k][tc * 4];
        float av[4] = {a4.x, a4.y, a4.z, a4.w};
        float bv[4] = {b4.x, b4.y, b4.z, b4.w};
        #pragma unroll
        for (int i = 0; i < 4; ++i)
            #pragma unroll
            for (int q = 0; q < 4; ++q)
                acc[i][q] += av[i] * bv[q];
    }

    float bb[4] = {0.f, 0.f, 0.f, 0.f};
    if (half == 0) {
        float4 b4 = *(const float4*)&b2[tc * 4];
        bb[0] = b4.x; bb[1] = b4.y; bb[2] = b4.z; bb[3] = b4.w;
    }
    #pragma unroll
    for (int i = 0; i < 4; ++i) {
        int node = n0 + tn * 4 + i;
        if (node >= N_NODES) break;
        float4 v;
        v.x = acc[i][0] + bb[0];
        v.y = acc[i][1] + bb[1];
        v.z = acc[i][2] + bb[2];
        v.w = acc[i][3] + bb[3];
        if (half == 0) *(float4*)&out[(size_t)node * OUTF + tc * 4] = v;
        else           *(float4*)&p  [(size_t)node * OUTF + tc * 4] = v;
    }
}

// ---------------- layer-2 neighbor aggregation (pull over p) ----------------
// 4 nodes per 256-thread block; lane j accumulates column j
__global__ void k_pull(const int* __restrict__ row_start, const int* __restrict__ csr_src,
                       const float* __restrict__ p, const float* __restrict__ invd,
                       float* __restrict__ out) {
    int n = blockIdx.x * 4 + (threadIdx.x >> 6);
    if (n >= N_NODES) return;
    int lane = threadIdx.x & 63;
    int b = row_start[n], e = row_start[n + 1];
    float acc = 0.0f;
    for (int i = b; i < e; ++i) {
        int s = csr_src[i];
        acc += p[(size_t)s * OUTF + lane];
    }
    out[(size_t)n * OUTF + lane] += acc * invd[n];
}

// ---------------- launcher ----------------

static inline size_t al256(size_t v) { return (v + 255) & ~(size_t)255; }

extern "C" void kernel_launch(void* const* d_in, const int* in_sizes, int n_in,
                              void* d_out, int out_size, void* d_ws, size_t ws_size,
                              hipStream_t stream) {
    const float* x   = (const float*)d_in[0];
    const int*   src = (const int*)d_in[1];
    const int*   dst = (const int*)d_in[2];
    const float* W1s = (const float*)d_in[3];
    const float* W1n = (const float*)d_in[4];
    const float* b1  = (const float*)d_in[5];
    const float* W2s = (const float*)d_in[6];
    const float* W2n = (const float*)d_in[7];
    const float* b2  = (const float*)d_in[8];
    float* out = (float*)d_out;

    char* ws = (char*)d_ws;
    size_t off = 0;
    int*   degi      = (int*)(ws + off); off += al256((size_t)N_NODES * 4);
    int*   row_start = (int*)(ws + off); off += al256((size_t)(N_NODES + 1) * 4);
    int*   cursor    = (int*)(ws + off); off += al256((size_t)N_NODES * 4);
    int*   csr_src   = (int*)(ws + off); off += al256((size_t)N_EDGES * 4);
    float* invd      = (float*)(ws + off); off += al256((size_t)N_NODES * 4);
    float* hn        = (float*)(ws + off); off += al256((size_t)N_NODES * 3 * 4);
    float* W2c       = (float*)(ws + off); off += al256((size_t)HID * 128 * 4);
    float* p         = (float*)(ws + off); off += al256((size_t)N_NODES * OUTF * 4);

    hipMemsetAsync(degi, 0, (size_t)N_NODES * 4, stream);

    {   // degree histogram
        int blocks = (N_EDGES + 255) / 256;
        k_hist<<<blocks, 256, 0, stream>>>(dst, degi);
    }
    k_scan<<<1, 1024, 0, stream>>>(degi, row_start, cursor, invd);
    {   // CSR scatter
        int blocks = (N_EDGES + 255) / 256;
        k_scatter<<<blocks, 256, 0, stream>>>(src, dst, cursor, csr_src);
    }
    {   // layer-1 neighbor mean (3 feats)
        int blocks = (N_NODES + 255) / 256;
        k_agg1<<<blocks, 256, 0, stream>>>(row_start, csr_src, x, invd, hn);
    }
    {   // W2 interleave
        int blocks = (HID * 128 + 255) / 256;
        k_prep_w2<<<blocks, 256, 0, stream>>>(W2s, W2n, W2c);
    }
    {   // fused layer1+layer2 GEMM
        dim3 grid((N_NODES + 63) / 64, 2);
        k_gemm<<<grid, 256, 0, stream>>>(x, hn, W1s, W1n, b1, W2c, b2, out, p);
    }
    {   // layer-2 neighbor aggregation (pull)
        int blocks = (N_NODES + 3) / 4;
        k_pull<<<blocks, 256, 0, stream>>>(row_start, csr_src, p, invd, out);
    }
}

// Round 3
// 492.344 us; speedup vs baseline: 1.8809x; 1.5428x over previous
//
#include <hip/hip_runtime.h>

#define N_NODES 100000
#define N_EDGES 1600000
#define HID 150
#define OUTF 64
#define NB 256                         // scan blocks
#define CH ((N_NODES + NB - 1) / NB)   // 391 elements per scan block

// ---------------- CSR build ----------------

__global__ void k_hist(const int* __restrict__ dst, int* __restrict__ degi) {
    int e = blockIdx.x * blockDim.x + threadIdx.x;
    if (e < N_EDGES) atomicAdd(&degi[dst[e]], 1);
}

// Phase A: per-block partial sums of degi
__global__ void k_psum(const int* __restrict__ degi, int* __restrict__ bsum) {
    __shared__ int red[256];
    int b0 = blockIdx.x * CH;
    int e = min(b0 + CH, N_NODES);
    int s = 0;
    for (int i = b0 + threadIdx.x; i < e; i += 256) s += degi[i];
    red[threadIdx.x] = s;
    __syncthreads();
    for (int o = 128; o > 0; o >>= 1) {
        if (threadIdx.x < o) red[threadIdx.x] += red[threadIdx.x + o];
        __syncthreads();
    }
    if (threadIdx.x == 0) bsum[blockIdx.x] = red[0];
}

// Phase B: single small block scans the 256 block sums -> exclusive boff
__global__ void k_bscan(const int* __restrict__ bsum, int* __restrict__ boff,
                        int* __restrict__ row_start) {
    __shared__ int sh[NB];
    int t = threadIdx.x;
    sh[t] = bsum[t];
    __syncthreads();
    for (int o = 1; o < NB; o <<= 1) {
        int v = sh[t];
        int vp = (t >= o) ? sh[t - o] : 0;
        __syncthreads();
        sh[t] = v + vp;
        __syncthreads();
    }
    boff[t] = (t > 0) ? sh[t - 1] : 0;
    if (t == NB - 1) row_start[N_NODES] = sh[NB - 1];
}

// Phase C: per-block exclusive scan of chunk + block offset -> row_start, cursor, invd
__global__ void k_apply(const int* __restrict__ degi, const int* __restrict__ boff,
                        int* __restrict__ row_start, int* __restrict__ cursor,
                        float* __restrict__ invd) {
    __shared__ int sh[256];
    int b0 = blockIdx.x * CH;
    int e = min(b0 + CH, N_NODES);
    int carry = boff[blockIdx.x];
    for (int base = b0; base < e; base += 256) {
        int i = base + threadIdx.x;
        int v = (i < e) ? degi[i] : 0;
        sh[threadIdx.x] = v;
        __syncthreads();
        for (int o = 1; o < 256; o <<= 1) {
            int a = sh[threadIdx.x];
            int ap = (threadIdx.x >= o) ? sh[threadIdx.x - o] : 0;
            __syncthreads();
            sh[threadIdx.x] = a + ap;
            __syncthreads();
        }
        int incl = sh[threadIdx.x];
        int excl = incl - v;
        if (i < e) {
            int rs = carry + excl;
            row_start[i] = rs;
            cursor[i] = rs;
            invd[i] = 1.0f / fmaxf((float)v, 1.0f);
        }
        int total = sh[255];
        __syncthreads();   // protect sh before next tile overwrites
        carry += total;
    }
}

__global__ void k_scatter(const int* __restrict__ src, const int* __restrict__ dst,
                          int* __restrict__ cursor, int* __restrict__ csr_src) {
    int e = blockIdx.x * blockDim.x + threadIdx.x;
    if (e >= N_EDGES) return;
    int idx = atomicAdd(&cursor[dst[e]], 1);
    csr_src[idx] = src[e];
}

// ---------------- layer-1 neighbor mean (pull, 3 feats) ----------------

__global__ void k_agg1(const int* __restrict__ row_start, const int* __restrict__ csr_src,
                       const float* __restrict__ x, const float* __restrict__ invd,
                       float* __restrict__ hn) {
    int n = blockIdx.x * blockDim.x + threadIdx.x;
    if (n >= N_NODES) return;
    int b = row_start[n], e = row_start[n + 1];
    float s0 = 0.f, s1 = 0.f, s2 = 0.f;
    for (int i = b; i < e; ++i) {
        int s = csr_src[i];
        s0 += x[s * 3 + 0];
        s1 += x[s * 3 + 1];
        s2 += x[s * 3 + 2];
    }
    float id = invd[n];
    hn[n * 3 + 0] = s0 * id;
    hn[n * 3 + 1] = s1 * id;
    hn[n * 3 + 2] = s2 * id;
}

// ---------------- W2 interleave: W2c[k][0..63]=W2s, [64..127]=W2n ----------------

__global__ void k_prep_w2(const float* __restrict__ W2s, const float* __restrict__ W2n,
                          float* __restrict__ W2c) {
    int idx = blockIdx.x * blockDim.x + threadIdx.x;
    if (idx >= HID * 128) return;
    int k = idx >> 7, j = idx & 127;
    W2c[idx] = (j < 64) ? W2s[k * 64 + j] : W2n[k * 64 + (j - 64)];
}

// ---------------- fused layer1 + layer2 GEMM ----------------
// grid.x = node tiles of 64, grid.y = 2 (0: self half -> out (+b2), 1: neigh half -> p)
// block 256 = 16 (node groups) x 16 (col groups), thread tile 4 nodes x 4 cols
__global__ __launch_bounds__(256, 2) void k_gemm(
        const float* __restrict__ x, const float* __restrict__ hn,
        const float* __restrict__ W1s, const float* __restrict__ W1n,
        const float* __restrict__ b1, const float* __restrict__ W2c,
        const float* __restrict__ b2,
        float* __restrict__ out, float* __restrict__ p) {
    __shared__ float shT[HID][64];   // h transposed: shT[k][n]   38.4 KB
    __shared__ float sW2[HID][64];   // W2 half tile: sW2[k][c]   38.4 KB
    const int half = blockIdx.y;
    const int n0 = blockIdx.x * 64;
    const int tid = threadIdx.x;

    for (int idx = tid; idx < HID * 64; idx += 256) {
        int k = idx >> 6, c = idx & 63;
        sW2[k][c] = W2c[k * 128 + half * 64 + c];
    }
    for (int idx = tid; idx < HID * 64; idx += 256) {
        int k = idx >> 6, n = idx & 63;
        int node = n0 + n;
        float h = 0.0f;
        if (node < N_NODES) {
            h = b1[k];
            #pragma unroll
            for (int i = 0; i < 3; ++i) {
                h += x[node * 3 + i] * W1s[i * HID + k]
                   + hn[node * 3 + i] * W1n[i * HID + k];
            }
            h = fmaxf(h, 0.0f);
        }
        shT[k][n] = h;
    }
    __syncthreads();

    const int tc = tid & 15;
    const int tn = tid >> 4;
    float acc[4][4];
    #pragma unroll
    for (int i = 0; i < 4; ++i)
        #pragma unroll
        for (int q = 0; q < 4; ++q) acc[i][q] = 0.0f;

    #pragma unroll 2
    for (int k = 0; k < HID; ++k) {
        float4 a4 = *(const float4*)&shT[k][tn * 4];
        float4 b4 = *(const float4*)&sW2[k][tc * 4];
        float av[4] = {a4.x, a4.y, a4.z, a4.w};
        float bv[4] = {b4.x, b4.y, b4.z, b4.w};
        #pragma unroll
        for (int i = 0; i < 4; ++i)
            #pragma unroll
            for (int q = 0; q < 4; ++q)
                acc[i][q] += av[i] * bv[q];
    }

    float bb[4] = {0.f, 0.f, 0.f, 0.f};
    if (half == 0) {
        float4 b4 = *(const float4*)&b2[tc * 4];
        bb[0] = b4.x; bb[1] = b4.y; bb[2] = b4.z; bb[3] = b4.w;
    }
    #pragma unroll
    for (int i = 0; i < 4; ++i) {
        int node = n0 + tn * 4 + i;
        if (node >= N_NODES) break;
        float4 v;
        v.x = acc[i][0] + bb[0];
        v.y = acc[i][1] + bb[1];
        v.z = acc[i][2] + bb[2];
        v.w = acc[i][3] + bb[3];
        if (half == 0) *(float4*)&out[(size_t)node * OUTF + tc * 4] = v;
        else           *(float4*)&p  [(size_t)node * OUTF + tc * 4] = v;
    }
}

// ---------------- layer-2 neighbor aggregation (pull over p) ----------------

__global__ void k_pull(const int* __restrict__ row_start, const int* __restrict__ csr_src,
                       const float* __restrict__ p, const float* __restrict__ invd,
                       float* __restrict__ out) {
    int n = blockIdx.x * 4 + (threadIdx.x >> 6);
    if (n >= N_NODES) return;
    int lane = threadIdx.x & 63;
    int b = row_start[n], e = row_start[n + 1];
    float acc = 0.0f;
    for (int i = b; i < e; ++i) {
        int s = csr_src[i];
        acc += p[(size_t)s * OUTF + lane];
    }
    out[(size_t)n * OUTF + lane] += acc * invd[n];
}

// ---------------- launcher ----------------

static inline size_t al256(size_t v) { return (v + 255) & ~(size_t)255; }

extern "C" void kernel_launch(void* const* d_in, const int* in_sizes, int n_in,
                              void* d_out, int out_size, void* d_ws, size_t ws_size,
                              hipStream_t stream) {
    const float* x   = (const float*)d_in[0];
    const int*   src = (const int*)d_in[1];
    const int*   dst = (const int*)d_in[2];
    const float* W1s = (const float*)d_in[3];
    const float* W1n = (const float*)d_in[4];
    const float* b1  = (const float*)d_in[5];
    const float* W2s = (const float*)d_in[6];
    const float* W2n = (const float*)d_in[7];
    const float* b2  = (const float*)d_in[8];
    float* out = (float*)d_out;

    char* ws = (char*)d_ws;
    size_t off = 0;
    int*   degi      = (int*)(ws + off); off += al256((size_t)N_NODES * 4);
    int*   row_start = (int*)(ws + off); off += al256((size_t)(N_NODES + 1) * 4);
    int*   cursor    = (int*)(ws + off); off += al256((size_t)N_NODES * 4);
    int*   csr_src   = (int*)(ws + off); off += al256((size_t)N_EDGES * 4);
    float* invd      = (float*)(ws + off); off += al256((size_t)N_NODES * 4);
    float* hn        = (float*)(ws + off); off += al256((size_t)N_NODES * 3 * 4);
    float* W2c       = (float*)(ws + off); off += al256((size_t)HID * 128 * 4);
    float* p         = (float*)(ws + off); off += al256((size_t)N_NODES * OUTF * 4);
    int*   bsum      = (int*)(ws + off); off += al256((size_t)NB * 4);
    int*   boff      = (int*)(ws + off); off += al256((size_t)NB * 4);

    hipMemsetAsync(degi, 0, (size_t)N_NODES * 4, stream);

    {   // degree histogram
        int blocks = (N_EDGES + 255) / 256;
        k_hist<<<blocks, 256, 0, stream>>>(dst, degi);
    }
    // 3-phase device-wide exclusive scan
    k_psum<<<NB, 256, 0, stream>>>(degi, bsum);
    k_bscan<<<1, NB, 0, stream>>>(bsum, boff, row_start);
    k_apply<<<NB, 256, 0, stream>>>(degi, boff, row_start, cursor, invd);
    {   // CSR scatter
        int blocks = (N_EDGES + 255) / 256;
        k_scatter<<<blocks, 256, 0, stream>>>(src, dst, cursor, csr_src);
    }
    {   // layer-1 neighbor mean (3 feats)
        int blocks = (N_NODES + 255) / 256;
        k_agg1<<<blocks, 256, 0, stream>>>(row_start, csr_src, x, invd, hn);
    }
    {   // W2 interleave
        int blocks = (HID * 128 + 255) / 256;
        k_prep_w2<<<blocks, 256, 0, stream>>>(W2s, W2n, W2c);
    }
    {   // fused layer1+layer2 GEMM
        dim3 grid((N_NODES + 63) / 64, 2);
        k_gemm<<<grid, 256, 0, stream>>>(x, hn, W1s, W1n, b1, W2c, b2, out, p);
    }
    {   // layer-2 neighbor aggregation (pull)
        int blocks = (N_NODES + 3) / 4;
        k_pull<<<blocks, 256, 0, stream>>>(row_start, csr_src, p, invd, out);
    }
}

// Round 4
// 401.127 us; speedup vs baseline: 2.3087x; 1.2274x over previous
//
#include <hip/hip_runtime.h>

#define N_NODES 100000
#define N_EDGES 1600000
#define HID 150
#define OUTF 64
#define NB 256                         // scan blocks
#define CH ((N_NODES + NB - 1) / NB)   // 391 elements per scan block

// ---------------- fused prep: zero degi, pad x -> x4, interleave W2 ----------------

__global__ void k_prep(const float* __restrict__ x, float4* __restrict__ x4,
                       const float* __restrict__ W2s, const float* __restrict__ W2n,
                       float* __restrict__ W2c, int* __restrict__ degi) {
    int idx = blockIdx.x * blockDim.x + threadIdx.x;
    if (idx < N_NODES) {
        degi[idx] = 0;
        x4[idx] = make_float4(x[idx * 3 + 0], x[idx * 3 + 1], x[idx * 3 + 2], 0.0f);
    }
    if (idx < HID * 128) {
        int k = idx >> 7, j = idx & 127;
        W2c[idx] = (j < 64) ? W2s[k * 64 + j] : W2n[k * 64 + (j - 64)];
    }
}

// ---------------- CSR build ----------------

__global__ void k_hist(const int* __restrict__ dst, int* __restrict__ degi) {
    int e = blockIdx.x * blockDim.x + threadIdx.x;
    if (e < N_EDGES) atomicAdd(&degi[dst[e]], 1);
}

__global__ void k_psum(const int* __restrict__ degi, int* __restrict__ bsum) {
    __shared__ int red[256];
    int b0 = blockIdx.x * CH;
    int e = min(b0 + CH, N_NODES);
    int s = 0;
    for (int i = b0 + threadIdx.x; i < e; i += 256) s += degi[i];
    red[threadIdx.x] = s;
    __syncthreads();
    for (int o = 128; o > 0; o >>= 1) {
        if (threadIdx.x < o) red[threadIdx.x] += red[threadIdx.x + o];
        __syncthreads();
    }
    if (threadIdx.x == 0) bsum[blockIdx.x] = red[0];
}

__global__ void k_bscan(const int* __restrict__ bsum, int* __restrict__ boff,
                        int* __restrict__ row_start) {
    __shared__ int sh[NB];
    int t = threadIdx.x;
    sh[t] = bsum[t];
    __syncthreads();
    for (int o = 1; o < NB; o <<= 1) {
        int v = sh[t];
        int vp = (t >= o) ? sh[t - o] : 0;
        __syncthreads();
        sh[t] = v + vp;
        __syncthreads();
    }
    boff[t] = (t > 0) ? sh[t - 1] : 0;
    if (t == NB - 1) row_start[N_NODES] = sh[NB - 1];
}

__global__ void k_apply(const int* __restrict__ degi, const int* __restrict__ boff,
                        int* __restrict__ row_start, int* __restrict__ cursor,
                        float* __restrict__ invd) {
    __shared__ int sh[256];
    int b0 = blockIdx.x * CH;
    int e = min(b0 + CH, N_NODES);
    int carry = boff[blockIdx.x];
    for (int base = b0; base < e; base += 256) {
        int i = base + threadIdx.x;
        int v = (i < e) ? degi[i] : 0;
        sh[threadIdx.x] = v;
        __syncthreads();
        for (int o = 1; o < 256; o <<= 1) {
            int a = sh[threadIdx.x];
            int ap = (threadIdx.x >= o) ? sh[threadIdx.x - o] : 0;
            __syncthreads();
            sh[threadIdx.x] = a + ap;
            __syncthreads();
        }
        int incl = sh[threadIdx.x];
        int excl = incl - v;
        if (i < e) {
            int rs = carry + excl;
            row_start[i] = rs;
            cursor[i] = rs;
            invd[i] = 1.0f / fmaxf((float)v, 1.0f);
        }
        int total = sh[255];
        __syncthreads();
        carry += total;
    }
}

__global__ void k_scatter(const int* __restrict__ src, const int* __restrict__ dst,
                          int* __restrict__ cursor, int* __restrict__ csr_src) {
    int e = blockIdx.x * blockDim.x + threadIdx.x;
    if (e >= N_EDGES) return;
    int idx = atomicAdd(&cursor[dst[e]], 1);
    csr_src[idx] = src[e];
}

// ---------------- layer-1 neighbor mean: 16 nodes/wave, 4 lanes/node ----------------

__global__ void k_agg1(const int* __restrict__ row_start, const int* __restrict__ csr_src,
                       const float4* __restrict__ x4, const float* __restrict__ invd,
                       float* __restrict__ hn) {
    int wid = (blockIdx.x * blockDim.x + threadIdx.x) >> 6;
    int lane = threadIdx.x & 63;
    int n = wid * 16 + (lane >> 2);
    if (n >= N_NODES) return;
    int sub = lane & 3;
    int b = row_start[n], e = row_start[n + 1];
    float s0 = 0.f, s1 = 0.f, s2 = 0.f;
    for (int i = b + sub; i < e; i += 4) {
        float4 v = x4[csr_src[i]];
        s0 += v.x; s1 += v.y; s2 += v.z;
    }
    s0 += __shfl_xor(s0, 1, 64); s0 += __shfl_xor(s0, 2, 64);
    s1 += __shfl_xor(s1, 1, 64); s1 += __shfl_xor(s1, 2, 64);
    s2 += __shfl_xor(s2, 1, 64); s2 += __shfl_xor(s2, 2, 64);
    if (sub == 0) {
        float id = invd[n];
        hn[n * 3 + 0] = s0 * id;
        hn[n * 3 + 1] = s1 * id;
        hn[n * 3 + 2] = s2 * id;
    }
}

// ---------------- fused layer1 + layer2 GEMM ----------------

__global__ __launch_bounds__(256, 2) void k_gemm(
        const float* __restrict__ x, const float* __restrict__ hn,
        const float* __restrict__ W1s, const float* __restrict__ W1n,
        const float* __restrict__ b1, const float* __restrict__ W2c,
        const float* __restrict__ b2,
        float* __restrict__ out, float* __restrict__ p) {
    __shared__ float shT[HID][64];
    __shared__ float sW2[HID][64];
    const int half = blockIdx.y;
    const int n0 = blockIdx.x * 64;
    const int tid = threadIdx.x;

    for (int idx = tid; idx < HID * 64; idx += 256) {
        int k = idx >> 6, c = idx & 63;
        sW2[k][c] = W2c[k * 128 + half * 64 + c];
    }
    for (int idx = tid; idx < HID * 64; idx += 256) {
        int k = idx >> 6, n = idx & 63;
        int node = n0 + n;
        float h = 0.0f;
        if (node < N_NODES) {
            h = b1[k];
            #pragma unroll
            for (int i = 0; i < 3; ++i) {
                h += x[node * 3 + i] * W1s[i * HID + k]
                   + hn[node * 3 + i] * W1n[i * HID + k];
            }
            h = fmaxf(h, 0.0f);
        }
        shT[k][n] = h;
    }
    __syncthreads();

    const int tc = tid & 15;
    const int tn = tid >> 4;
    float acc[4][4];
    #pragma unroll
    for (int i = 0; i < 4; ++i)
        #pragma unroll
        for (int q = 0; q < 4; ++q) acc[i][q] = 0.0f;

    #pragma unroll 2
    for (int k = 0; k < HID; ++k) {
        float4 a4 = *(const float4*)&shT[k][tn * 4];
        float4 b4 = *(const float4*)&sW2[k][tc * 4];
        float av[4] = {a4.x, a4.y, a4.z, a4.w};
        float bv[4] = {b4.x, b4.y, b4.z, b4.w};
        #pragma unroll
        for (int i = 0; i < 4; ++i)
            #pragma unroll
            for (int q = 0; q < 4; ++q)
                acc[i][q] += av[i] * bv[q];
    }

    float bb[4] = {0.f, 0.f, 0.f, 0.f};
    if (half == 0) {
        float4 b4 = *(const float4*)&b2[tc * 4];
        bb[0] = b4.x; bb[1] = b4.y; bb[2] = b4.z; bb[3] = b4.w;
    }
    #pragma unroll
    for (int i = 0; i < 4; ++i) {
        int node = n0 + tn * 4 + i;
        if (node >= N_NODES) break;
        float4 v;
        v.x = acc[i][0] + bb[0];
        v.y = acc[i][1] + bb[1];
        v.z = acc[i][2] + bb[2];
        v.w = acc[i][3] + bb[3];
        if (half == 0) *(float4*)&out[(size_t)node * OUTF + tc * 4] = v;
        else           *(float4*)&p  [(size_t)node * OUTF + tc * 4] = v;
    }
}

// ---------------- layer-2 pull: 4 edge-groups x 16 col-lanes per wave ----------------

__global__ void k_pull(const int* __restrict__ row_start, const int* __restrict__ csr_src,
                       const float* __restrict__ p, const float* __restrict__ invd,
                       float* __restrict__ out) {
    int n = blockIdx.x * 4 + (threadIdx.x >> 6);
    if (n >= N_NODES) return;
    int lane = threadIdx.x & 63;
    int egrp = lane >> 4;    // 0..3 : which edge in the group of 4
    int c4 = lane & 15;      // col chunk: cols c4*4 .. +3
    int b = row_start[n], e = row_start[n + 1];
    float4 acc = make_float4(0.f, 0.f, 0.f, 0.f);
    for (int i = b + egrp; i < e; i += 4) {
        int s = csr_src[i];
        float4 v = *(const float4*)&p[(size_t)s * OUTF + c4 * 4];
        acc.x += v.x; acc.y += v.y; acc.z += v.z; acc.w += v.w;
    }
    // reduce across the 4 edge-groups (lane bits 4 and 5)
    acc.x += __shfl_xor(acc.x, 16, 64);
    acc.y += __shfl_xor(acc.y, 16, 64);
    acc.z += __shfl_xor(acc.z, 16, 64);
    acc.w += __shfl_xor(acc.w, 16, 64);
    acc.x += __shfl_xor(acc.x, 32, 64);
    acc.y += __shfl_xor(acc.y, 32, 64);
    acc.z += __shfl_xor(acc.z, 32, 64);
    acc.w += __shfl_xor(acc.w, 32, 64);
    if (egrp == 0) {
        float id = invd[n];
        float4 o = *(const float4*)&out[(size_t)n * OUTF + c4 * 4];
        o.x += acc.x * id;
        o.y += acc.y * id;
        o.z += acc.z * id;
        o.w += acc.w * id;
        *(float4*)&out[(size_t)n * OUTF + c4 * 4] = o;
    }
}

// ---------------- launcher ----------------

static inline size_t al256(size_t v) { return (v + 255) & ~(size_t)255; }

extern "C" void kernel_launch(void* const* d_in, const int* in_sizes, int n_in,
                              void* d_out, int out_size, void* d_ws, size_t ws_size,
                              hipStream_t stream) {
    const float* x   = (const float*)d_in[0];
    const int*   src = (const int*)d_in[1];
    const int*   dst = (const int*)d_in[2];
    const float* W1s = (const float*)d_in[3];
    const float* W1n = (const float*)d_in[4];
    const float* b1  = (const float*)d_in[5];
    const float* W2s = (const float*)d_in[6];
    const float* W2n = (const float*)d_in[7];
    const float* b2  = (const float*)d_in[8];
    float* out = (float*)d_out;

    char* ws = (char*)d_ws;
    size_t off = 0;
    int*   degi      = (int*)(ws + off); off += al256((size_t)N_NODES * 4);
    int*   row_start = (int*)(ws + off); off += al256((size_t)(N_NODES + 1) * 4);
    int*   cursor    = (int*)(ws + off); off += al256((size_t)N_NODES * 4);
    int*   csr_src   = (int*)(ws + off); off += al256((size_t)N_EDGES * 4);
    float* invd      = (float*)(ws + off); off += al256((size_t)N_NODES * 4);
    float* hn        = (float*)(ws + off); off += al256((size_t)N_NODES * 3 * 4);
    float* W2c       = (float*)(ws + off); off += al256((size_t)HID * 128 * 4);
    float* p         = (float*)(ws + off); off += al256((size_t)N_NODES * OUTF * 4);
    int*   bsum      = (int*)(ws + off); off += al256((size_t)NB * 4);
    int*   boff     = (int*)(ws + off); off += al256((size_t)NB * 4);
    float4* x4       = (float4*)(ws + off); off += al256((size_t)N_NODES * 16);

    {   // fused prep (zero degi, pad x, interleave W2)
        int blocks = (N_NODES + 255) / 256;
        k_prep<<<blocks, 256, 0, stream>>>(x, x4, W2s, W2n, W2c, degi);
    }
    {   // degree histogram
        int blocks = (N_EDGES + 255) / 256;
        k_hist<<<blocks, 256, 0, stream>>>(dst, degi);
    }
    k_psum<<<NB, 256, 0, stream>>>(degi, bsum);
    k_bscan<<<1, NB, 0, stream>>>(bsum, boff, row_start);
    k_apply<<<NB, 256, 0, stream>>>(degi, boff, row_start, cursor, invd);
    {   // CSR scatter
        int blocks = (N_EDGES + 255) / 256;
        k_scatter<<<blocks, 256, 0, stream>>>(src, dst, cursor, csr_src);
    }
    {   // layer-1 neighbor mean (16 nodes/wave)
        int waves = (N_NODES + 15) / 16;
        int blocks = (waves * 64 + 255) / 256;
        k_agg1<<<blocks, 256, 0, stream>>>(row_start, csr_src, x4, invd, hn);
    }
    {   // fused layer1+layer2 GEMM
        dim3 grid((N_NODES + 63) / 64, 2);
        k_gemm<<<grid, 256, 0, stream>>>(x, hn, W1s, W1n, b1, W2c, b2, out, p);
    }
    {   // layer-2 neighbor aggregation (pull)
        int blocks = (N_NODES + 3) / 4;
        k_pull<<<blocks, 256, 0, stream>>>(row_start, csr_src, p, invd, out);
    }
}

// Round 5
// 356.990 us; speedup vs baseline: 2.5941x; 1.1236x over previous
//
#include <hip/hip_runtime.h>

#define N_NODES 100000
#define N_EDGES 1600000
#define HID 150
#define OUTF 64
#define NB 256                         // scan blocks
#define CH ((N_NODES + NB - 1) / NB)   // 391 elements per scan block

// ---------------- fused prep: zero degi, pad x -> x4 ----------------

__global__ void k_prep(const float* __restrict__ x, float4* __restrict__ x4,
                       int* __restrict__ degi) {
    int idx = blockIdx.x * blockDim.x + threadIdx.x;
    if (idx < N_NODES) {
        degi[idx] = 0;
        x4[idx] = make_float4(x[idx * 3 + 0], x[idx * 3 + 1], x[idx * 3 + 2], 0.0f);
    }
}

// ---------------- CSR build ----------------

__global__ void k_hist(const int* __restrict__ dst, int* __restrict__ degi) {
    int e = blockIdx.x * blockDim.x + threadIdx.x;
    if (e < N_EDGES) atomicAdd(&degi[dst[e]], 1);
}

__global__ void k_psum(const int* __restrict__ degi, int* __restrict__ bsum) {
    __shared__ int red[256];
    int b0 = blockIdx.x * CH;
    int e = min(b0 + CH, N_NODES);
    int s = 0;
    for (int i = b0 + threadIdx.x; i < e; i += 256) s += degi[i];
    red[threadIdx.x] = s;
    __syncthreads();
    for (int o = 128; o > 0; o >>= 1) {
        if (threadIdx.x < o) red[threadIdx.x] += red[threadIdx.x + o];
        __syncthreads();
    }
    if (threadIdx.x == 0) bsum[blockIdx.x] = red[0];
}

__global__ void k_bscan(const int* __restrict__ bsum, int* __restrict__ boff,
                        int* __restrict__ row_start) {
    __shared__ int sh[NB];
    int t = threadIdx.x;
    sh[t] = bsum[t];
    __syncthreads();
    for (int o = 1; o < NB; o <<= 1) {
        int v = sh[t];
        int vp = (t >= o) ? sh[t - o] : 0;
        __syncthreads();
        sh[t] = v + vp;
        __syncthreads();
    }
    boff[t] = (t > 0) ? sh[t - 1] : 0;
    if (t == NB - 1) row_start[N_NODES] = sh[NB - 1];
}

__global__ void k_apply(const int* __restrict__ degi, const int* __restrict__ boff,
                        int* __restrict__ row_start, int* __restrict__ cursor,
                        float* __restrict__ invd) {
    __shared__ int sh[256];
    int b0 = blockIdx.x * CH;
    int e = min(b0 + CH, N_NODES);
    int carry = boff[blockIdx.x];
    for (int base = b0; base < e; base += 256) {
        int i = base + threadIdx.x;
        int v = (i < e) ? degi[i] : 0;
        sh[threadIdx.x] = v;
        __syncthreads();
        for (int o = 1; o < 256; o <<= 1) {
            int a = sh[threadIdx.x];
            int ap = (threadIdx.x >= o) ? sh[threadIdx.x - o] : 0;
            __syncthreads();
            sh[threadIdx.x] = a + ap;
            __syncthreads();
        }
        int incl = sh[threadIdx.x];
        int excl = incl - v;
        if (i < e) {
            int rs = carry + excl;
            row_start[i] = rs;
            cursor[i] = rs;
            invd[i] = 1.0f / fmaxf((float)v, 1.0f);
        }
        int total = sh[255];
        __syncthreads();
        carry += total;
    }
}

__global__ void k_scatter(const int* __restrict__ src, const int* __restrict__ dst,
                          int* __restrict__ cursor, int* __restrict__ csr_src) {
    int e = blockIdx.x * blockDim.x + threadIdx.x;
    if (e >= N_EDGES) return;
    int idx = atomicAdd(&cursor[dst[e]], 1);
    csr_src[idx] = src[e];
}

// ---------------- layer-1 neighbor mean: 16 nodes/wave, 4 lanes/node ----------------

__global__ void k_agg1(const int* __restrict__ row_start, const int* __restrict__ csr_src,
                       const float4* __restrict__ x4, const float* __restrict__ invd,
                       float4* __restrict__ hn4) {
    int wid = (blockIdx.x * blockDim.x + threadIdx.x) >> 6;
    int lane = threadIdx.x & 63;
    int n = wid * 16 + (lane >> 2);
    if (n >= N_NODES) return;
    int sub = lane & 3;
    int b = row_start[n], e = row_start[n + 1];
    float s0 = 0.f, s1 = 0.f, s2 = 0.f;
    for (int i = b + sub; i < e; i += 4) {
        float4 v = x4[csr_src[i]];
        s0 += v.x; s1 += v.y; s2 += v.z;
    }
    s0 += __shfl_xor(s0, 1, 64); s0 += __shfl_xor(s0, 2, 64);
    s1 += __shfl_xor(s1, 1, 64); s1 += __shfl_xor(s1, 2, 64);
    s2 += __shfl_xor(s2, 1, 64); s2 += __shfl_xor(s2, 2, 64);
    if (sub == 0) {
        float id = invd[n];
        hn4[n] = make_float4(s0 * id, s1 * id, s2 * id, 0.0f);
    }
}

// ---------------- fused layer1 + layer2 GEMM (both halves in one block) ----------------
// 64-node tile; 256 threads = 16 node-groups (tn=tid&15) x 16 col-groups (tc=tid>>4)
// thread tile: 4 nodes x 8 cols. cols 0-63 (tc<8): self half -> out (+b2)
//                                cols 64-127 (tc>=8): neigh half -> p
// Only shT in LDS (38.4 KB -> 4 blocks/CU). W2 read from global (L1/L2-hot, 76.8 KB total).
__global__ __launch_bounds__(256, 4) void k_gemm(
        const float4* __restrict__ x4, const float4* __restrict__ hn4,
        const float* __restrict__ W1s, const float* __restrict__ W1n,
        const float* __restrict__ b1,
        const float* __restrict__ W2s, const float* __restrict__ W2n,
        const float* __restrict__ b2,
        float* __restrict__ out, float* __restrict__ p) {
    __shared__ float shT[HID][64];   // h transposed: shT[k][n]   38.4 KB
    const int n0 = blockIdx.x * 64;
    const int tid = threadIdx.x;

    // ---- fused layer1 staging: wave w handles k = w, w+4, ... (W1/b1 wave-uniform)
    {
        int n = tid & 63;
        int node = n0 + n;
        int w = tid >> 6;
        float4 xs = make_float4(0.f, 0.f, 0.f, 0.f);
        float4 xn = make_float4(0.f, 0.f, 0.f, 0.f);
        if (node < N_NODES) { xs = x4[node]; xn = hn4[node]; }
        for (int k = w; k < HID; k += 4) {
            float h = b1[k]
                    + xs.x * W1s[0 * HID + k] + xs.y * W1s[1 * HID + k] + xs.z * W1s[2 * HID + k]
                    + xn.x * W1n[0 * HID + k] + xn.y * W1n[1 * HID + k] + xn.z * W1n[2 * HID + k];
            shT[k][n] = fmaxf(h, 0.0f);
        }
    }
    __syncthreads();

    const int tn = tid & 15;        // node group: nodes tn*4 .. +3
    const int tc = tid >> 4;        // col group 0..15
    const int cb = (tc & 7) * 8;    // col base within the 64-col half
    const float* __restrict__ Wsel = (tc < 8) ? W2s : W2n;

    float acc[4][8];
    #pragma unroll
    for (int i = 0; i < 4; ++i)
        #pragma unroll
        for (int q = 0; q < 8; ++q) acc[i][q] = 0.0f;

    #pragma unroll 2
    for (int k = 0; k < HID; ++k) {
        float4 a4 = *(const float4*)&shT[k][tn * 4];
        float4 w0 = *(const float4*)&Wsel[k * 64 + cb];
        float4 w1 = *(const float4*)&Wsel[k * 64 + cb + 4];
        float av[4] = {a4.x, a4.y, a4.z, a4.w};
        float wv[8] = {w0.x, w0.y, w0.z, w0.w, w1.x, w1.y, w1.z, w1.w};
        #pragma unroll
        for (int i = 0; i < 4; ++i)
            #pragma unroll
            for (int q = 0; q < 8; ++q)
                acc[i][q] += av[i] * wv[q];
    }

    float bb[8];
    #pragma unroll
    for (int q = 0; q < 8; ++q) bb[q] = 0.0f;
    if (tc < 8) {
        float4 b40 = *(const float4*)&b2[cb];
        float4 b41 = *(const float4*)&b2[cb + 4];
        bb[0] = b40.x; bb[1] = b40.y; bb[2] = b40.z; bb[3] = b40.w;
        bb[4] = b41.x; bb[5] = b41.y; bb[6] = b41.z; bb[7] = b41.w;
    }
    float* __restrict__ dest = (tc < 8) ? out : p;
    #pragma unroll
    for (int i = 0; i < 4; ++i) {
        int node = n0 + tn * 4 + i;
        if (node >= N_NODES) break;
        float4 v0, v1;
        v0.x = acc[i][0] + bb[0]; v0.y = acc[i][1] + bb[1];
        v0.z = acc[i][2] + bb[2]; v0.w = acc[i][3] + bb[3];
        v1.x = acc[i][4] + bb[4]; v1.y = acc[i][5] + bb[5];
        v1.z = acc[i][6] + bb[6]; v1.w = acc[i][7] + bb[7];
        *(float4*)&dest[(size_t)node * OUTF + cb]     = v0;
        *(float4*)&dest[(size_t)node * OUTF + cb + 4] = v1;
    }
}

// ---------------- layer-2 pull: 4 edge-groups x 16 col-lanes per wave ----------------

__global__ void k_pull(const int* __restrict__ row_start, const int* __restrict__ csr_src,
                       const float* __restrict__ p, const float* __restrict__ invd,
                       float* __restrict__ out) {
    int n = blockIdx.x * 4 + (threadIdx.x >> 6);
    if (n >= N_NODES) return;
    int lane = threadIdx.x & 63;
    int egrp = lane >> 4;
    int c4 = lane & 15;
    int b = row_start[n], e = row_start[n + 1];
    float4 acc = make_float4(0.f, 0.f, 0.f, 0.f);
    for (int i = b + egrp; i < e; i += 4) {
        int s = csr_src[i];
        float4 v = *(const float4*)&p[(size_t)s * OUTF + c4 * 4];
        acc.x += v.x; acc.y += v.y; acc.z += v.z; acc.w += v.w;
    }
    acc.x += __shfl_xor(acc.x, 16, 64);
    acc.y += __shfl_xor(acc.y, 16, 64);
    acc.z += __shfl_xor(acc.z, 16, 64);
    acc.w += __shfl_xor(acc.w, 16, 64);
    acc.x += __shfl_xor(acc.x, 32, 64);
    acc.y += __shfl_xor(acc.y, 32, 64);
    acc.z += __shfl_xor(acc.z, 32, 64);
    acc.w += __shfl_xor(acc.w, 32, 64);
    if (egrp == 0) {
        float id = invd[n];
        float4 o = *(const float4*)&out[(size_t)n * OUTF + c4 * 4];
        o.x += acc.x * id;
        o.y += acc.y * id;
        o.z += acc.z * id;
        o.w += acc.w * id;
        *(float4*)&out[(size_t)n * OUTF + c4 * 4] = o;
    }
}

// ---------------- launcher ----------------

static inline size_t al256(size_t v) { return (v + 255) & ~(size_t)255; }

extern "C" void kernel_launch(void* const* d_in, const int* in_sizes, int n_in,
                              void* d_out, int out_size, void* d_ws, size_t ws_size,
                              hipStream_t stream) {
    const float* x   = (const float*)d_in[0];
    const int*   src = (const int*)d_in[1];
    const int*   dst = (const int*)d_in[2];
    const float* W1s = (const float*)d_in[3];
    const float* W1n = (const float*)d_in[4];
    const float* b1  = (const float*)d_in[5];
    const float* W2s = (const float*)d_in[6];
    const float* W2n = (const float*)d_in[7];
    const float* b2  = (const float*)d_in[8];
    float* out = (float*)d_out;

    char* ws = (char*)d_ws;
    size_t off = 0;
    int*   degi      = (int*)(ws + off); off += al256((size_t)N_NODES * 4);
    int*   row_start = (int*)(ws + off); off += al256((size_t)(N_NODES + 1) * 4);
    int*   cursor    = (int*)(ws + off); off += al256((size_t)N_NODES * 4);
    int*   csr_src   = (int*)(ws + off); off += al256((size_t)N_EDGES * 4);
    float* invd      = (float*)(ws + off); off += al256((size_t)N_NODES * 4);
    float* p         = (float*)(ws + off); off += al256((size_t)N_NODES * OUTF * 4);
    int*   bsum      = (int*)(ws + off); off += al256((size_t)NB * 4);
    int*   boff      = (int*)(ws + off); off += al256((size_t)NB * 4);
    float4* x4       = (float4*)(ws + off); off += al256((size_t)N_NODES * 16);
    float4* hn4      = (float4*)(ws + off); off += al256((size_t)N_NODES * 16);

    {   // fused prep (zero degi, pad x)
        int blocks = (N_NODES + 255) / 256;
        k_prep<<<blocks, 256, 0, stream>>>(x, x4, degi);
    }
    {   // degree histogram
        int blocks = (N_EDGES + 255) / 256;
        k_hist<<<blocks, 256, 0, stream>>>(dst, degi);
    }
    k_psum<<<NB, 256, 0, stream>>>(degi, bsum);
    k_bscan<<<1, NB, 0, stream>>>(bsum, boff, row_start);
    k_apply<<<NB, 256, 0, stream>>>(degi, boff, row_start, cursor, invd);
    {   // CSR scatter
        int blocks = (N_EDGES + 255) / 256;
        k_scatter<<<blocks, 256, 0, stream>>>(src, dst, cursor, csr_src);
    }
    {   // layer-1 neighbor mean (16 nodes/wave)
        int waves = (N_NODES + 15) / 16;
        int blocks = (waves * 64 + 255) / 256;
        k_agg1<<<blocks, 256, 0, stream>>>(row_start, csr_src, x4, invd, hn4);
    }
    {   // fused layer1+layer2 GEMM (both halves)
        int blocks = (N_NODES + 63) / 64;
        k_gemm<<<blocks, 256, 0, stream>>>(x4, hn4, W1s, W1n, b1, W2s, W2n, b2, out, p);
    }
    {   // layer-2 neighbor aggregation (pull)
        int blocks = (N_NODES + 3) / 4;
        k_pull<<<blocks, 256, 0, stream>>>(row_start, csr_src, p, invd, out);
    }
}

// Round 6
// 235.491 us; speedup vs baseline: 3.9325x; 1.5159x over previous
//
#include <hip/hip_runtime.h>

#define N_NODES 100000
#define N_EDGES 1600000
#define HID 150
#define OUTF 64
#define NB 256                         // scan blocks
#define CH ((N_NODES + NB - 1) / NB)   // 391 elements per scan block
#define BSH 9                          // 512 nodes per bucket
#define BUKN 512                       // nodes per bucket
#define NBUK ((N_NODES + BUKN - 1) / BUKN)   // 196 buckets
#define TILE 4096                      // edges per partition tile
#define NTILE ((N_EDGES + TILE - 1) / TILE)  // 391 tiles

// ---------------- prep: pad x -> x4, bucket histogram of dst ----------------
// grid = NTILE(391) blocks x 256 threads; block also pads 256 nodes.
__global__ __launch_bounds__(256) void k_prep(const float* __restrict__ x,
                                              float4* __restrict__ x4,
                                              const int* __restrict__ dst,
                                              int* __restrict__ bukcnt) {
    __shared__ int cnt[NBUK];
    int tid = threadIdx.x;
    for (int i = tid; i < NBUK; i += 256) cnt[i] = 0;
    int idx = blockIdx.x * 256 + tid;
    if (idx < N_NODES)
        x4[idx] = make_float4(x[idx * 3 + 0], x[idx * 3 + 1], x[idx * 3 + 2], 0.0f);
    __syncthreads();
    int e0 = blockIdx.x * TILE;
    #pragma unroll
    for (int j = 0; j < 16; ++j) {
        int e = e0 + tid + j * 256;
        if (e < N_EDGES) atomicAdd(&cnt[dst[e] >> BSH], 1);
    }
    __syncthreads();
    for (int i = tid; i < NBUK; i += 256)
        if (cnt[i]) atomicAdd(&bukcnt[i], cnt[i]);
}

// ---------------- bucket scan: bukcnt -> bukoff (exclusive), zero bukcur ----------------
__global__ __launch_bounds__(256) void k_bukscan(const int* __restrict__ bukcnt,
                                                 int* __restrict__ bukoff,
                                                 int* __restrict__ bukcur) {
    __shared__ int sh[256];
    int t = threadIdx.x;
    int v = (t < NBUK) ? bukcnt[t] : 0;
    sh[t] = v;
    __syncthreads();
    for (int o = 1; o < 256; o <<= 1) {
        int a = sh[t];
        int ap = (t >= o) ? sh[t - o] : 0;
        __syncthreads();
        sh[t] = a + ap;
        __syncthreads();
    }
    if (t < NBUK) { bukoff[t] = sh[t] - v; bukcur[t] = 0; }
    if (t == 255) bukoff[NBUK] = sh[NBUK - 1];
}

// ---------------- multisplit partition: edges -> bucket-grouped pairbuf ----------------
// packed edge: (dst_local<<17) | src   (src < 2^17, dst_local < 512)
__global__ __launch_bounds__(256) void k_part(const int* __restrict__ src,
                                              const int* __restrict__ dst,
                                              const int* __restrict__ bukoff,
                                              int* __restrict__ bukcur,
                                              unsigned int* __restrict__ pairbuf) {
    __shared__ int cnt[NBUK];
    __shared__ int sbase[NBUK];
    __shared__ int gbase[NBUK];
    __shared__ int stmp[256];
    __shared__ unsigned int buf[TILE];
    __shared__ unsigned short bid[TILE];
    int tid = threadIdx.x;
    int e0 = blockIdx.x * TILE;
    int n = min(TILE, N_EDGES - e0);

    for (int i = tid; i < NBUK; i += 256) cnt[i] = 0;
    __syncthreads();

    int myb[16];
    int mypos[16];
    unsigned int myv[16];
    #pragma unroll
    for (int j = 0; j < 16; ++j) {
        int idx = tid + j * 256;
        myb[j] = -1;
        if (idx < n) {
            int s = src[e0 + idx];
            int d = dst[e0 + idx];
            int b = d >> BSH;
            myb[j] = b;
            myv[j] = ((unsigned int)(d & (BUKN - 1)) << 17) | (unsigned int)s;
            mypos[j] = atomicAdd(&cnt[b], 1);
        }
    }
    __syncthreads();

    // exclusive scan of cnt -> sbase
    int v = (tid < NBUK) ? cnt[tid] : 0;
    stmp[tid] = v;
    __syncthreads();
    for (int o = 1; o < 256; o <<= 1) {
        int a = stmp[tid];
        int ap = (tid >= o) ? stmp[tid - o] : 0;
        __syncthreads();
        stmp[tid] = a + ap;
        __syncthreads();
    }
    if (tid < NBUK) {
        sbase[tid] = stmp[tid] - v;
        gbase[tid] = atomicAdd(&bukcur[tid], v);
    }
    __syncthreads();

    // place into reorder buffer
    #pragma unroll
    for (int j = 0; j < 16; ++j) {
        if (myb[j] >= 0) {
            int slot = sbase[myb[j]] + mypos[j];
            buf[slot] = myv[j];
            bid[slot] = (unsigned short)myb[j];
        }
    }
    __syncthreads();

    // bucket-grouped copy-out (runs are contiguous per bucket)
    for (int slot = tid; slot < n; slot += 256) {
        int b = bid[slot];
        pairbuf[bukoff[b] + gbase[b] + (slot - sbase[b])] = buf[slot];
    }
}

// ---------------- per-bucket degree histogram -> dense degi ----------------
__global__ __launch_bounds__(256) void k_bdeg(const int* __restrict__ bukoff,
                                              const unsigned int* __restrict__ pairbuf,
                                              int* __restrict__ degi) {
    __shared__ int deg[BUKN];
    int tid = threadIdx.x;
    int b = blockIdx.x;
    int n0 = b << BSH;
    for (int i = tid; i < BUKN; i += 256) deg[i] = 0;
    __syncthreads();
    int lo = bukoff[b], hi = bukoff[b + 1];
    for (int i = lo + tid; i < hi; i += 256)
        atomicAdd(&deg[pairbuf[i] >> 17], 1);
    __syncthreads();
    for (int i = tid; i < BUKN; i += 256) {
        int node = n0 + i;
        if (node < N_NODES) degi[node] = deg[i];
    }
}

// ---------------- device-wide scan of degi -> row_start, invd ----------------

__global__ void k_psum(const int* __restrict__ degi, int* __restrict__ bsum) {
    __shared__ int red[256];
    int b0 = blockIdx.x * CH;
    int e = min(b0 + CH, N_NODES);
    int s = 0;
    for (int i = b0 + threadIdx.x; i < e; i += 256) s += degi[i];
    red[threadIdx.x] = s;
    __syncthreads();
    for (int o = 128; o > 0; o >>= 1) {
        if (threadIdx.x < o) red[threadIdx.x] += red[threadIdx.x + o];
        __syncthreads();
    }
    if (threadIdx.x == 0) bsum[blockIdx.x] = red[0];
}

__global__ void k_bscan(const int* __restrict__ bsum, int* __restrict__ boff,
                        int* __restrict__ row_start) {
    __shared__ int sh[NB];
    int t = threadIdx.x;
    sh[t] = bsum[t];
    __syncthreads();
    for (int o = 1; o < NB; o <<= 1) {
        int v = sh[t];
        int vp = (t >= o) ? sh[t - o] : 0;
        __syncthreads();
        sh[t] = v + vp;
        __syncthreads();
    }
    boff[t] = (t > 0) ? sh[t - 1] : 0;
    if (t == NB - 1) row_start[N_NODES] = sh[NB - 1];
}

__global__ void k_apply(const int* __restrict__ degi, const int* __restrict__ boff,
                        int* __restrict__ row_start, float* __restrict__ invd) {
    __shared__ int sh[256];
    int b0 = blockIdx.x * CH;
    int e = min(b0 + CH, N_NODES);
    int carry = boff[blockIdx.x];
    for (int base = b0; base < e; base += 256) {
        int i = base + threadIdx.x;
        int v = (i < e) ? degi[i] : 0;
        sh[threadIdx.x] = v;
        __syncthreads();
        for (int o = 1; o < 256; o <<= 1) {
            int a = sh[threadIdx.x];
            int ap = (threadIdx.x >= o) ? sh[threadIdx.x - o] : 0;
            __syncthreads();
            sh[threadIdx.x] = a + ap;
            __syncthreads();
        }
        int incl = sh[threadIdx.x];
        int excl = incl - v;
        if (i < e) {
            row_start[i] = carry + excl;
            invd[i] = 1.0f / fmaxf((float)v, 1.0f);
        }
        int total = sh[255];
        __syncthreads();
        carry += total;
    }
}

// ---------------- per-bucket fine scatter: pairbuf -> csr_src (LDS cursors) ----------------
__global__ __launch_bounds__(256) void k_fine(const int* __restrict__ bukoff,
                                              const unsigned int* __restrict__ pairbuf,
                                              const int* __restrict__ row_start,
                                              int* __restrict__ csr_src) {
    __shared__ int cur[BUKN];
    int tid = threadIdx.x;
    int b = blockIdx.x;
    int n0 = b << BSH;
    for (int i = tid; i < BUKN; i += 256) {
        int node = n0 + i;
        cur[i] = (node < N_NODES) ? row_start[node] : 0;
    }
    __syncthreads();
    int lo = bukoff[b], hi = bukoff[b + 1];
    for (int i = lo + tid; i < hi; i += 256) {
        unsigned int v = pairbuf[i];
        int dl = v >> 17;
        int s = (int)(v & 0x1FFFF);
        int ofs = atomicAdd(&cur[dl], 1);
        csr_src[ofs] = s;
    }
}

// ---------------- layer-1 neighbor mean: 16 nodes/wave, 4 lanes/node ----------------

__global__ void k_agg1(const int* __restrict__ row_start, const int* __restrict__ csr_src,
                       const float4* __restrict__ x4, const float* __restrict__ invd,
                       float4* __restrict__ hn4) {
    int wid = (blockIdx.x * blockDim.x + threadIdx.x) >> 6;
    int lane = threadIdx.x & 63;
    int n = wid * 16 + (lane >> 2);
    if (n >= N_NODES) return;
    int sub = lane & 3;
    int b = row_start[n], e = row_start[n + 1];
    float s0 = 0.f, s1 = 0.f, s2 = 0.f;
    for (int i = b + sub; i < e; i += 4) {
        float4 v = x4[csr_src[i]];
        s0 += v.x; s1 += v.y; s2 += v.z;
    }
    s0 += __shfl_xor(s0, 1, 64); s0 += __shfl_xor(s0, 2, 64);
    s1 += __shfl_xor(s1, 1, 64); s1 += __shfl_xor(s1, 2, 64);
    s2 += __shfl_xor(s2, 1, 64); s2 += __shfl_xor(s2, 2, 64);
    if (sub == 0) {
        float id = invd[n];
        hn4[n] = make_float4(s0 * id, s1 * id, s2 * id, 0.0f);
    }
}

// ---------------- fused layer1 + layer2 GEMM (both halves in one block) ----------------

__global__ __launch_bounds__(256, 4) void k_gemm(
        const float4* __restrict__ x4, const float4* __restrict__ hn4,
        const float* __restrict__ W1s, const float* __restrict__ W1n,
        const float* __restrict__ b1,
        const float* __restrict__ W2s, const float* __restrict__ W2n,
        const float* __restrict__ b2,
        float* __restrict__ out, float* __restrict__ p) {
    __shared__ float shT[HID][64];
    const int n0 = blockIdx.x * 64;
    const int tid = threadIdx.x;

    {
        int n = tid & 63;
        int node = n0 + n;
        int w = tid >> 6;
        float4 xs = make_float4(0.f, 0.f, 0.f, 0.f);
        float4 xn = make_float4(0.f, 0.f, 0.f, 0.f);
        if (node < N_NODES) { xs = x4[node]; xn = hn4[node]; }
        for (int k = w; k < HID; k += 4) {
            float h = b1[k]
                    + xs.x * W1s[0 * HID + k] + xs.y * W1s[1 * HID + k] + xs.z * W1s[2 * HID + k]
                    + xn.x * W1n[0 * HID + k] + xn.y * W1n[1 * HID + k] + xn.z * W1n[2 * HID + k];
            shT[k][n] = fmaxf(h, 0.0f);
        }
    }
    __syncthreads();

    const int tn = tid & 15;
    const int tc = tid >> 4;
    const int cb = (tc & 7) * 8;
    const float* __restrict__ Wsel = (tc < 8) ? W2s : W2n;

    float acc[4][8];
    #pragma unroll
    for (int i = 0; i < 4; ++i)
        #pragma unroll
        for (int q = 0; q < 8; ++q) acc[i][q] = 0.0f;

    #pragma unroll 2
    for (int k = 0; k < HID; ++k) {
        float4 a4 = *(const float4*)&shT[k][tn * 4];
        float4 w0 = *(const float4*)&Wsel[k * 64 + cb];
        float4 w1 = *(const float4*)&Wsel[k * 64 + cb + 4];
        float av[4] = {a4.x, a4.y, a4.z, a4.w};
        float wv[8] = {w0.x, w0.y, w0.z, w0.w, w1.x, w1.y, w1.z, w1.w};
        #pragma unroll
        for (int i = 0; i < 4; ++i)
            #pragma unroll
            for (int q = 0; q < 8; ++q)
                acc[i][q] += av[i] * wv[q];
    }

    float bb[8];
    #pragma unroll
    for (int q = 0; q < 8; ++q) bb[q] = 0.0f;
    if (tc < 8) {
        float4 b40 = *(const float4*)&b2[cb];
        float4 b41 = *(const float4*)&b2[cb + 4];
        bb[0] = b40.x; bb[1] = b40.y; bb[2] = b40.z; bb[3] = b40.w;
        bb[4] = b41.x; bb[5] = b41.y; bb[6] = b41.z; bb[7] = b41.w;
    }
    float* __restrict__ dest = (tc < 8) ? out : p;
    #pragma unroll
    for (int i = 0; i < 4; ++i) {
        int node = n0 + tn * 4 + i;
        if (node >= N_NODES) break;
        float4 v0, v1;
        v0.x = acc[i][0] + bb[0]; v0.y = acc[i][1] + bb[1];
        v0.z = acc[i][2] + bb[2]; v0.w = acc[i][3] + bb[3];
        v1.x = acc[i][4] + bb[4]; v1.y = acc[i][5] + bb[5];
        v1.z = acc[i][6] + bb[6]; v1.w = acc[i][7] + bb[7];
        *(float4*)&dest[(size_t)node * OUTF + cb]     = v0;
        *(float4*)&dest[(size_t)node * OUTF + cb + 4] = v1;
    }
}

// ---------------- layer-2 pull: 4 edge-groups x 16 col-lanes per wave ----------------

__global__ void k_pull(const int* __restrict__ row_start, const int* __restrict__ csr_src,
                       const float* __restrict__ p, const float* __restrict__ invd,
                       float* __restrict__ out) {
    int n = blockIdx.x * 4 + (threadIdx.x >> 6);
    if (n >= N_NODES) return;
    int lane = threadIdx.x & 63;
    int egrp = lane >> 4;
    int c4 = lane & 15;
    int b = row_start[n], e = row_start[n + 1];
    float4 acc = make_float4(0.f, 0.f, 0.f, 0.f);
    for (int i = b + egrp; i < e; i += 4) {
        int s = csr_src[i];
        float4 v = *(const float4*)&p[(size_t)s * OUTF + c4 * 4];
        acc.x += v.x; acc.y += v.y; acc.z += v.z; acc.w += v.w;
    }
    acc.x += __shfl_xor(acc.x, 16, 64);
    acc.y += __shfl_xor(acc.y, 16, 64);
    acc.z += __shfl_xor(acc.z, 16, 64);
    acc.w += __shfl_xor(acc.w, 16, 64);
    acc.x += __shfl_xor(acc.x, 32, 64);
    acc.y += __shfl_xor(acc.y, 32, 64);
    acc.z += __shfl_xor(acc.z, 32, 64);
    acc.w += __shfl_xor(acc.w, 32, 64);
    if (egrp == 0) {
        float id = invd[n];
        float4 o = *(const float4*)&out[(size_t)n * OUTF + c4 * 4];
        o.x += acc.x * id;
        o.y += acc.y * id;
        o.z += acc.z * id;
        o.w += acc.w * id;
        *(float4*)&out[(size_t)n * OUTF + c4 * 4] = o;
    }
}

// ---------------- launcher ----------------

static inline size_t al256(size_t v) { return (v + 255) & ~(size_t)255; }

extern "C" void kernel_launch(void* const* d_in, const int* in_sizes, int n_in,
                              void* d_out, int out_size, void* d_ws, size_t ws_size,
                              hipStream_t stream) {
    const float* x   = (const float*)d_in[0];
    const int*   src = (const int*)d_in[1];
    const int*   dst = (const int*)d_in[2];
    const float* W1s = (const float*)d_in[3];
    const float* W1n = (const float*)d_in[4];
    const float* b1  = (const float*)d_in[5];
    const float* W2s = (const float*)d_in[6];
    const float* W2n = (const float*)d_in[7];
    const float* b2  = (const float*)d_in[8];
    float* out = (float*)d_out;

    char* ws = (char*)d_ws;
    size_t off = 0;
    int*   degi      = (int*)(ws + off); off += al256((size_t)N_NODES * 4);
    int*   row_start = (int*)(ws + off); off += al256((size_t)(N_NODES + 1) * 4);
    int*   csr_src   = (int*)(ws + off); off += al256((size_t)N_EDGES * 4);
    float* invd      = (float*)(ws + off); off += al256((size_t)N_NODES * 4);
    float* p         = (float*)(ws + off); off += al256((size_t)N_NODES * OUTF * 4);
    int*   bsum      = (int*)(ws + off); off += al256((size_t)NB * 4);
    int*   boff      = (int*)(ws + off); off += al256((size_t)NB * 4);
    float4* x4       = (float4*)(ws + off); off += al256((size_t)N_NODES * 16);
    float4* hn4      = (float4*)(ws + off); off += al256((size_t)N_NODES * 16);
    unsigned int* pairbuf = (unsigned int*)(ws + off); off += al256((size_t)N_EDGES * 4);
    int*   bukcnt    = (int*)(ws + off); off += al256((size_t)NBUK * 4);
    int*   bukoff    = (int*)(ws + off); off += al256((size_t)(NBUK + 1) * 4);
    int*   bukcur    = (int*)(ws + off); off += al256((size_t)NBUK * 4);

    hipMemsetAsync(bukcnt, 0, (size_t)NBUK * 4, stream);

    // prep: x4 pad + bucket histogram
    k_prep<<<NTILE, 256, 0, stream>>>(x, x4, dst, bukcnt);
    // bucket offsets
    k_bukscan<<<1, 256, 0, stream>>>(bukcnt, bukoff, bukcur);
    // multisplit partition
    k_part<<<NTILE, 256, 0, stream>>>(src, dst, bukoff, bukcur, pairbuf);
    // per-bucket degrees (dense write)
    k_bdeg<<<NBUK, 256, 0, stream>>>(bukoff, pairbuf, degi);
    // device-wide scan -> row_start, invd
    k_psum<<<NB, 256, 0, stream>>>(degi, bsum);
    k_bscan<<<1, NB, 0, stream>>>(bsum, boff, row_start);
    k_apply<<<NB, 256, 0, stream>>>(degi, boff, row_start, invd);
    // per-bucket fine scatter -> csr_src
    k_fine<<<NBUK, 256, 0, stream>>>(bukoff, pairbuf, row_start, csr_src);
    {   // layer-1 neighbor mean (16 nodes/wave)
        int waves = (N_NODES + 15) / 16;
        int blocks = (waves * 64 + 255) / 256;
        k_agg1<<<blocks, 256, 0, stream>>>(row_start, csr_src, x4, invd, hn4);
    }
    {   // fused layer1+layer2 GEMM (both halves)
        int blocks = (N_NODES + 63) / 64;
        k_gemm<<<blocks, 256, 0, stream>>>(x4, hn4, W1s, W1n, b1, W2s, W2n, b2, out, p);
    }
    {   // layer-2 neighbor aggregation (pull)
        int blocks = (N_NODES + 3) / 4;
        k_pull<<<blocks, 256, 0, stream>>>(row_start, csr_src, p, invd, out);
    }
}

// Round 7
// 193.222 us; speedup vs baseline: 4.7928x; 1.2188x over previous
//
#include <hip/hip_runtime.h>

#define N_NODES 100000
#define N_EDGES 1600000
#define HID 150
#define KPAD 160
#define OUTF 64
#define NB 256                         // scan blocks
#define CH ((N_NODES + NB - 1) / NB)   // 391 elements per scan block
#define BSH 9                          // 512 nodes per bucket
#define BUKN 512                       // nodes per bucket
#define NBUK ((N_NODES + BUKN - 1) / BUKN)   // 196 buckets
#define TILE 4096                      // edges per partition tile
#define NTILE ((N_EDGES + TILE - 1) / TILE)  // 391 tiles

typedef short bf16x8 __attribute__((ext_vector_type(8)));
typedef float f32x4 __attribute__((ext_vector_type(4)));

__device__ __forceinline__ unsigned short f2bf(float f) {
    union { float f; unsigned u; } v; v.f = f;
    unsigned r = (v.u + 0x7FFFu + ((v.u >> 16) & 1u)) >> 16;
    return (unsigned short)r;
}

// ---------------- prep: pad x -> x4, bucket histogram of dst, W1t/W2T pack ----------------
// grid = NTILE(391) blocks x 256 threads.
__global__ __launch_bounds__(256) void k_prep(const float* __restrict__ x,
                                              float4* __restrict__ x4,
                                              const int* __restrict__ dst,
                                              int* __restrict__ bukcnt,
                                              const float* __restrict__ W1s,
                                              const float* __restrict__ W1n,
                                              const float* __restrict__ b1,
                                              const float* __restrict__ W2s,
                                              const float* __restrict__ W2n,
                                              float* __restrict__ W1t,
                                              unsigned short* __restrict__ W2T) {
    __shared__ int cnt[NBUK];
    int tid = threadIdx.x;
    for (int i = tid; i < NBUK; i += 256) cnt[i] = 0;
    int idx = blockIdx.x * 256 + tid;
    if (idx < N_NODES)
        x4[idx] = make_float4(x[idx * 3 + 0], x[idx * 3 + 1], x[idx * 3 + 2], 0.0f);
    // W1t[k][8] = {W1s[0][k],W1s[1][k],W1s[2][k],b1[k], W1n[0][k],W1n[1][k],W1n[2][k],0}
    if (idx < KPAD) {
        int k = idx;
        bool ok = (k < HID);
        W1t[k * 8 + 0] = ok ? W1s[0 * HID + k] : 0.0f;
        W1t[k * 8 + 1] = ok ? W1s[1 * HID + k] : 0.0f;
        W1t[k * 8 + 2] = ok ? W1s[2 * HID + k] : 0.0f;
        W1t[k * 8 + 3] = ok ? b1[k] : 0.0f;
        W1t[k * 8 + 4] = ok ? W1n[0 * HID + k] : 0.0f;
        W1t[k * 8 + 5] = ok ? W1n[1 * HID + k] : 0.0f;
        W1t[k * 8 + 6] = ok ? W1n[2 * HID + k] : 0.0f;
        W1t[k * 8 + 7] = 0.0f;
    }
    // W2T[c][k] bf16: c<64 -> W2s[k][c], else W2n[k][c-64]; 0 for k>=150
    if (idx < 128 * KPAD) {
        int c = idx / KPAD, k = idx - c * KPAD;
        float v = 0.0f;
        if (k < HID) v = (c < 64) ? W2s[k * 64 + c] : W2n[k * 64 + (c - 64)];
        W2T[idx] = f2bf(v);
    }
    __syncthreads();
    int e0 = blockIdx.x * TILE;
    #pragma unroll
    for (int j = 0; j < 16; ++j) {
        int e = e0 + tid + j * 256;
        if (e < N_EDGES) atomicAdd(&cnt[dst[e] >> BSH], 1);
    }
    __syncthreads();
    for (int i = tid; i < NBUK; i += 256)
        if (cnt[i]) atomicAdd(&bukcnt[i], cnt[i]);
}

// ---------------- bucket scan ----------------
__global__ __launch_bounds__(256) void k_bukscan(const int* __restrict__ bukcnt,
                                                 int* __restrict__ bukoff,
                                                 int* __restrict__ bukcur) {
    __shared__ int sh[256];
    int t = threadIdx.x;
    int v = (t < NBUK) ? bukcnt[t] : 0;
    sh[t] = v;
    __syncthreads();
    for (int o = 1; o < 256; o <<= 1) {
        int a = sh[t];
        int ap = (t >= o) ? sh[t - o] : 0;
        __syncthreads();
        sh[t] = a + ap;
        __syncthreads();
    }
    if (t < NBUK) { bukoff[t] = sh[t] - v; bukcur[t] = 0; }
    if (t == 255) bukoff[NBUK] = sh[NBUK - 1];
}

// ---------------- multisplit partition ----------------
__global__ __launch_bounds__(256) void k_part(const int* __restrict__ src,
                                              const int* __restrict__ dst,
                                              const int* __restrict__ bukoff,
                                              int* __restrict__ bukcur,
                                              unsigned int* __restrict__ pairbuf) {
    __shared__ int cnt[NBUK];
    __shared__ int sbase[NBUK];
    __shared__ int gbase[NBUK];
    __shared__ int stmp[256];
    __shared__ unsigned int buf[TILE];
    __shared__ unsigned short bid[TILE];
    int tid = threadIdx.x;
    int e0 = blockIdx.x * TILE;
    int n = min(TILE, N_EDGES - e0);

    for (int i = tid; i < NBUK; i += 256) cnt[i] = 0;
    __syncthreads();

    int myb[16];
    int mypos[16];
    unsigned int myv[16];
    #pragma unroll
    for (int j = 0; j < 16; ++j) {
        int idx = tid + j * 256;
        myb[j] = -1;
        if (idx < n) {
            int s = src[e0 + idx];
            int d = dst[e0 + idx];
            int b = d >> BSH;
            myb[j] = b;
            myv[j] = ((unsigned int)(d & (BUKN - 1)) << 17) | (unsigned int)s;
            mypos[j] = atomicAdd(&cnt[b], 1);
        }
    }
    __syncthreads();

    int v = (tid < NBUK) ? cnt[tid] : 0;
    stmp[tid] = v;
    __syncthreads();
    for (int o = 1; o < 256; o <<= 1) {
        int a = stmp[tid];
        int ap = (tid >= o) ? stmp[tid - o] : 0;
        __syncthreads();
        stmp[tid] = a + ap;
        __syncthreads();
    }
    if (tid < NBUK) {
        sbase[tid] = stmp[tid] - v;
        gbase[tid] = atomicAdd(&bukcur[tid], v);
    }
    __syncthreads();

    #pragma unroll
    for (int j = 0; j < 16; ++j) {
        if (myb[j] >= 0) {
            int slot = sbase[myb[j]] + mypos[j];
            buf[slot] = myv[j];
            bid[slot] = (unsigned short)myb[j];
        }
    }
    __syncthreads();

    for (int slot = tid; slot < n; slot += 256) {
        int b = bid[slot];
        pairbuf[bukoff[b] + gbase[b] + (slot - sbase[b])] = buf[slot];
    }
}

// ---------------- per-bucket degree histogram ----------------
__global__ __launch_bounds__(256) void k_bdeg(const int* __restrict__ bukoff,
                                              const unsigned int* __restrict__ pairbuf,
                                              int* __restrict__ degi) {
    __shared__ int deg[BUKN];
    int tid = threadIdx.x;
    int b = blockIdx.x;
    int n0 = b << BSH;
    for (int i = tid; i < BUKN; i += 256) deg[i] = 0;
    __syncthreads();
    int lo = bukoff[b], hi = bukoff[b + 1];
    for (int i = lo + tid; i < hi; i += 256)
        atomicAdd(&deg[pairbuf[i] >> 17], 1);
    __syncthreads();
    for (int i = tid; i < BUKN; i += 256) {
        int node = n0 + i;
        if (node < N_NODES) degi[node] = deg[i];
    }
}

// ---------------- device-wide scan of degi ----------------

__global__ void k_psum(const int* __restrict__ degi, int* __restrict__ bsum) {
    __shared__ int red[256];
    int b0 = blockIdx.x * CH;
    int e = min(b0 + CH, N_NODES);
    int s = 0;
    for (int i = b0 + threadIdx.x; i < e; i += 256) s += degi[i];
    red[threadIdx.x] = s;
    __syncthreads();
    for (int o = 128; o > 0; o >>= 1) {
        if (threadIdx.x < o) red[threadIdx.x] += red[threadIdx.x + o];
        __syncthreads();
    }
    if (threadIdx.x == 0) bsum[blockIdx.x] = red[0];
}

__global__ void k_bscan(const int* __restrict__ bsum, int* __restrict__ boff,
                        int* __restrict__ row_start) {
    __shared__ int sh[NB];
    int t = threadIdx.x;
    sh[t] = bsum[t];
    __syncthreads();
    for (int o = 1; o < NB; o <<= 1) {
        int v = sh[t];
        int vp = (t >= o) ? sh[t - o] : 0;
        __syncthreads();
        sh[t] = v + vp;
        __syncthreads();
    }
    boff[t] = (t > 0) ? sh[t - 1] : 0;
    if (t == NB - 1) row_start[N_NODES] = sh[NB - 1];
}

__global__ void k_apply(const int* __restrict__ degi, const int* __restrict__ boff,
                        int* __restrict__ row_start, float* __restrict__ invd) {
    __shared__ int sh[256];
    int b0 = blockIdx.x * CH;
    int e = min(b0 + CH, N_NODES);
    int carry = boff[blockIdx.x];
    for (int base = b0; base < e; base += 256) {
        int i = base + threadIdx.x;
        int v = (i < e) ? degi[i] : 0;
        sh[threadIdx.x] = v;
        __syncthreads();
        for (int o = 1; o < 256; o <<= 1) {
            int a = sh[threadIdx.x];
            int ap = (threadIdx.x >= o) ? sh[threadIdx.x - o] : 0;
            __syncthreads();
            sh[threadIdx.x] = a + ap;
            __syncthreads();
        }
        int incl = sh[threadIdx.x];
        int excl = incl - v;
        if (i < e) {
            row_start[i] = carry + excl;
            invd[i] = 1.0f / fmaxf((float)v, 1.0f);
        }
        int total = sh[255];
        __syncthreads();
        carry += total;
    }
}

// ---------------- per-bucket fine scatter ----------------
__global__ __launch_bounds__(256) void k_fine(const int* __restrict__ bukoff,
                                              const unsigned int* __restrict__ pairbuf,
                                              const int* __restrict__ row_start,
                                              int* __restrict__ csr_src) {
    __shared__ int cur[BUKN];
    int tid = threadIdx.x;
    int b = blockIdx.x;
    int n0 = b << BSH;
    for (int i = tid; i < BUKN; i += 256) {
        int node = n0 + i;
        cur[i] = (node < N_NODES) ? row_start[node] : 0;
    }
    __syncthreads();
    int lo = bukoff[b], hi = bukoff[b + 1];
    for (int i = lo + tid; i < hi; i += 256) {
        unsigned int v = pairbuf[i];
        int dl = v >> 17;
        int s = (int)(v & 0x1FFFF);
        int ofs = atomicAdd(&cur[dl], 1);
        csr_src[ofs] = s;
    }
}

// ---------------- layer-1 neighbor mean ----------------

__global__ void k_agg1(const int* __restrict__ row_start, const int* __restrict__ csr_src,
                       const float4* __restrict__ x4, const float* __restrict__ invd,
                       float4* __restrict__ hn4) {
    int wid = (blockIdx.x * blockDim.x + threadIdx.x) >> 6;
    int lane = threadIdx.x & 63;
    int n = wid * 16 + (lane >> 2);
    if (n >= N_NODES) return;
    int sub = lane & 3;
    int b = row_start[n], e = row_start[n + 1];
    float s0 = 0.f, s1 = 0.f, s2 = 0.f;
    for (int i = b + sub; i < e; i += 4) {
        float4 v = x4[csr_src[i]];
        s0 += v.x; s1 += v.y; s2 += v.z;
    }
    s0 += __shfl_xor(s0, 1, 64); s0 += __shfl_xor(s0, 2, 64);
    s1 += __shfl_xor(s1, 1, 64); s1 += __shfl_xor(s1, 2, 64);
    s2 += __shfl_xor(s2, 1, 64); s2 += __shfl_xor(s2, 2, 64);
    if (sub == 0) {
        float id = invd[n];
        hn4[n] = make_float4(s0 * id, s1 * id, s2 * id, 0.0f);
    }
}

// ---------------- fused layer1 + layer2 GEMM via bf16 MFMA ----------------
// Block = 256 threads (4 waves), 64-node tile, 128 output cols (0-63 self -> out,
// 64-127 neigh -> p). K = 150 padded to 160.
// Stage: h computed fp32 -> bf16 into shA[64][168] (k-contiguous, 16B-aligned rows).
// Wave w owns rows w*16..+15; A-frag = 1 ds_read_b128; B-frag = 1 global b128 from
// bf16 W2T[128][160] (40 KB, L1-hot). 40 MFMA per wave.
#define SHK 168
__global__ __launch_bounds__(256, 4) void k_gemm(
        const float4* __restrict__ x4, const float4* __restrict__ hn4,
        const float* __restrict__ W1t,
        const unsigned short* __restrict__ W2T,
        const float* __restrict__ b2,
        float* __restrict__ out, float* __restrict__ p) {
    __shared__ unsigned short shA[64 * SHK];   // 21.5 KB
    const int n0 = blockIdx.x * 64;
    const int tid = threadIdx.x;

    // ---- staging: thread (n = tid&63) computes k-pairs k = 2*(tid>>6) + 8j
    {
        int n = tid & 63;
        int node = n0 + n;
        int kbase = 2 * (tid >> 6);
        float4 xs = make_float4(0.f, 0.f, 0.f, 0.f);
        float4 xn = make_float4(0.f, 0.f, 0.f, 0.f);
        if (node < N_NODES) { xs = x4[node]; xn = hn4[node]; }
        #pragma unroll 4
        for (int j = 0; j < 20; ++j) {
            int k = kbase + 8 * j;
            float4 wa0 = *(const float4*)&W1t[k * 8 + 0];
            float4 wb0 = *(const float4*)&W1t[k * 8 + 4];
            float4 wa1 = *(const float4*)&W1t[(k + 1) * 8 + 0];
            float4 wb1 = *(const float4*)&W1t[(k + 1) * 8 + 4];
            float h0 = wa0.w + xs.x * wa0.x + xs.y * wa0.y + xs.z * wa0.z
                             + xn.x * wb0.x + xn.y * wb0.y + xn.z * wb0.z;
            float h1 = wa1.w + xs.x * wa1.x + xs.y * wa1.y + xs.z * wa1.z
                             + xn.x * wb1.x + xn.y * wb1.y + xn.z * wb1.z;
            h0 = fmaxf(h0, 0.0f);
            h1 = fmaxf(h1, 0.0f);
            unsigned int pk = (unsigned int)f2bf(h0) | ((unsigned int)f2bf(h1) << 16);
            *(unsigned int*)&shA[n * SHK + k] = pk;
        }
    }
    __syncthreads();

    // ---- MFMA phase
    const int lane = tid & 63;
    const int w = tid >> 6;
    const int c16 = lane & 15;
    const int quad = lane >> 4;
    const int ko = quad * 8;

    f32x4 acc[8];
    #pragma unroll
    for (int t = 0; t < 8; ++t) acc[t] = (f32x4){0.f, 0.f, 0.f, 0.f};

    #pragma unroll
    for (int ks = 0; ks < 5; ++ks) {
        int k0 = ks * 32;
        bf16x8 a = *(const bf16x8*)&shA[(w * 16 + c16) * SHK + k0 + ko];
        #pragma unroll
        for (int t = 0; t < 8; ++t) {
            bf16x8 b = *(const bf16x8*)&W2T[(t * 16 + c16) * KPAD + k0 + ko];
            acc[t] = __builtin_amdgcn_mfma_f32_16x16x32_bf16(a, b, acc[t], 0, 0, 0);
        }
    }

    // ---- epilogue: D row = quad*4 + i (within wave's 16 rows), col = t*16 + c16
    const int rbase = n0 + w * 16 + quad * 4;
    #pragma unroll
    for (int t = 0; t < 8; ++t) {
        int gc = t * 16 + c16;
        float badd = (t < 4) ? b2[gc] : 0.0f;
        float* __restrict__ dstp = (t < 4) ? out : p;
        int cc = (t < 4) ? gc : gc - 64;
        #pragma unroll
        for (int i = 0; i < 4; ++i) {
            int node = rbase + i;
            if (node < N_NODES) dstp[(size_t)node * OUTF + cc] = acc[t][i] + badd;
        }
    }
}

// ---------------- layer-2 pull ----------------

__global__ void k_pull(const int* __restrict__ row_start, const int* __restrict__ csr_src,
                       const float* __restrict__ p, const float* __restrict__ invd,
                       float* __restrict__ out) {
    int n = blockIdx.x * 4 + (threadIdx.x >> 6);
    if (n >= N_NODES) return;
    int lane = threadIdx.x & 63;
    int egrp = lane >> 4;
    int c4 = lane & 15;
    int b = row_start[n], e = row_start[n + 1];
    float4 acc = make_float4(0.f, 0.f, 0.f, 0.f);
    for (int i = b + egrp; i < e; i += 4) {
        int s = csr_src[i];
        float4 v = *(const float4*)&p[(size_t)s * OUTF + c4 * 4];
        acc.x += v.x; acc.y += v.y; acc.z += v.z; acc.w += v.w;
    }
    acc.x += __shfl_xor(acc.x, 16, 64);
    acc.y += __shfl_xor(acc.y, 16, 64);
    acc.z += __shfl_xor(acc.z, 16, 64);
    acc.w += __shfl_xor(acc.w, 16, 64);
    acc.x += __shfl_xor(acc.x, 32, 64);
    acc.y += __shfl_xor(acc.y, 32, 64);
    acc.z += __shfl_xor(acc.z, 32, 64);
    acc.w += __shfl_xor(acc.w, 32, 64);
    if (egrp == 0) {
        float id = invd[n];
        float4 o = *(const float4*)&out[(size_t)n * OUTF + c4 * 4];
        o.x += acc.x * id;
        o.y += acc.y * id;
        o.z += acc.z * id;
        o.w += acc.w * id;
        *(float4*)&out[(size_t)n * OUTF + c4 * 4] = o;
    }
}

// ---------------- launcher ----------------

static inline size_t al256(size_t v) { return (v + 255) & ~(size_t)255; }

extern "C" void kernel_launch(void* const* d_in, const int* in_sizes, int n_in,
                              void* d_out, int out_size, void* d_ws, size_t ws_size,
                              hipStream_t stream) {
    const float* x   = (const float*)d_in[0];
    const int*   src = (const int*)d_in[1];
    const int*   dst = (const int*)d_in[2];
    const float* W1s = (const float*)d_in[3];
    const float* W1n = (const float*)d_in[4];
    const float* b1  = (const float*)d_in[5];
    const float* W2s = (const float*)d_in[6];
    const float* W2n = (const float*)d_in[7];
    const float* b2  = (const float*)d_in[8];
    float* out = (float*)d_out;

    char* ws = (char*)d_ws;
    size_t off = 0;
    int*   degi      = (int*)(ws + off); off += al256((size_t)N_NODES * 4);
    int*   row_start = (int*)(ws + off); off += al256((size_t)(N_NODES + 1) * 4);
    int*   csr_src   = (int*)(ws + off); off += al256((size_t)N_EDGES * 4);
    float* invd      = (float*)(ws + off); off += al256((size_t)N_NODES * 4);
    float* p         = (float*)(ws + off); off += al256((size_t)N_NODES * OUTF * 4);
    int*   bsum      = (int*)(ws + off); off += al256((size_t)NB * 4);
    int*   boff      = (int*)(ws + off); off += al256((size_t)NB * 4);
    float4* x4       = (float4*)(ws + off); off += al256((size_t)N_NODES * 16);
    float4* hn4      = (float4*)(ws + off); off += al256((size_t)N_NODES * 16);
    unsigned int* pairbuf = (unsigned int*)(ws + off); off += al256((size_t)N_EDGES * 4);
    int*   bukcnt    = (int*)(ws + off); off += al256((size_t)NBUK * 4);
    int*   bukoff    = (int*)(ws + off); off += al256((size_t)(NBUK + 1) * 4);
    int*   bukcur    = (int*)(ws + off); off += al256((size_t)NBUK * 4);
    float* W1t       = (float*)(ws + off); off += al256((size_t)KPAD * 8 * 4);
    unsigned short* W2T = (unsigned short*)(ws + off); off += al256((size_t)128 * KPAD * 2);

    hipMemsetAsync(bukcnt, 0, (size_t)NBUK * 4, stream);

    // prep: x4 pad + bucket histogram + W1t/W2T pack
    k_prep<<<NTILE, 256, 0, stream>>>(x, x4, dst, bukcnt, W1s, W1n, b1, W2s, W2n, W1t, W2T);
    k_bukscan<<<1, 256, 0, stream>>>(bukcnt, bukoff, bukcur);
    k_part<<<NTILE, 256, 0, stream>>>(src, dst, bukoff, bukcur, pairbuf);
    k_bdeg<<<NBUK, 256, 0, stream>>>(bukoff, pairbuf, degi);
    k_psum<<<NB, 256, 0, stream>>>(degi, bsum);
    k_bscan<<<1, NB, 0, stream>>>(bsum, boff, row_start);
    k_apply<<<NB, 256, 0, stream>>>(degi, boff, row_start, invd);
    k_fine<<<NBUK, 256, 0, stream>>>(bukoff, pairbuf, row_start, csr_src);
    {   // layer-1 neighbor mean
        int waves = (N_NODES + 15) / 16;
        int blocks = (waves * 64 + 255) / 256;
        k_agg1<<<blocks, 256, 0, stream>>>(row_start, csr_src, x4, invd, hn4);
    }
    {   // fused layer1+layer2 GEMM (bf16 MFMA)
        int blocks = (N_NODES + 63) / 64;
        k_gemm<<<blocks, 256, 0, stream>>>(x4, hn4, W1t, W2T, b2, out, p);
    }
    {   // layer-2 neighbor aggregation (pull)
        int blocks = (N_NODES + 3) / 4;
        k_pull<<<blocks, 256, 0, stream>>>(row_start, csr_src, p, invd, out);
    }
}

// Round 8
// 172.306 us; speedup vs baseline: 5.3746x; 1.1214x over previous
//
#include <hip/hip_runtime.h>

#define N_NODES 100000
#define N_EDGES 1600000
#define HID 150
#define KPAD 160
#define OUTF 64
#define NB 256                         // scan blocks
#define CH ((N_NODES + NB - 1) / NB)   // 391 elements per scan block
#define BSH 9                          // 512 nodes per bucket
#define BUKN 512                       // nodes per bucket
#define NBUK ((N_NODES + BUKN - 1) / BUKN)   // 196 buckets
#define TILE 4096                      // edges per partition tile
#define NTILE ((N_EDGES + TILE - 1) / TILE)  // 391 tiles

typedef short bf16x8 __attribute__((ext_vector_type(8)));
typedef float f32x4 __attribute__((ext_vector_type(4)));

__device__ __forceinline__ unsigned short f2bf(float f) {
    union { float f; unsigned u; } v; v.f = f;
    unsigned r = (v.u + 0x7FFFu + ((v.u >> 16) & 1u)) >> 16;
    return (unsigned short)r;
}

__device__ __forceinline__ float bf2f(unsigned short b) {
    union { unsigned u; float f; } v;
    v.u = ((unsigned)b) << 16;
    return v.f;
}

// ---------------- prep: pad x -> x4, bucket histogram of dst, W1t/W2T pack ----------------
__global__ __launch_bounds__(256) void k_prep(const float* __restrict__ x,
                                              float4* __restrict__ x4,
                                              const int* __restrict__ dst,
                                              int* __restrict__ bukcnt,
                                              const float* __restrict__ W1s,
                                              const float* __restrict__ W1n,
                                              const float* __restrict__ b1,
                                              const float* __restrict__ W2s,
                                              const float* __restrict__ W2n,
                                              float* __restrict__ W1t,
                                              unsigned short* __restrict__ W2T) {
    __shared__ int cnt[NBUK];
    int tid = threadIdx.x;
    for (int i = tid; i < NBUK; i += 256) cnt[i] = 0;
    int idx = blockIdx.x * 256 + tid;
    if (idx < N_NODES)
        x4[idx] = make_float4(x[idx * 3 + 0], x[idx * 3 + 1], x[idx * 3 + 2], 0.0f);
    if (idx < KPAD) {
        int k = idx;
        bool ok = (k < HID);
        W1t[k * 8 + 0] = ok ? W1s[0 * HID + k] : 0.0f;
        W1t[k * 8 + 1] = ok ? W1s[1 * HID + k] : 0.0f;
        W1t[k * 8 + 2] = ok ? W1s[2 * HID + k] : 0.0f;
        W1t[k * 8 + 3] = ok ? b1[k] : 0.0f;
        W1t[k * 8 + 4] = ok ? W1n[0 * HID + k] : 0.0f;
        W1t[k * 8 + 5] = ok ? W1n[1 * HID + k] : 0.0f;
        W1t[k * 8 + 6] = ok ? W1n[2 * HID + k] : 0.0f;
        W1t[k * 8 + 7] = 0.0f;
    }
    if (idx < 128 * KPAD) {
        int c = idx / KPAD, k = idx - c * KPAD;
        float v = 0.0f;
        if (k < HID) v = (c < 64) ? W2s[k * 64 + c] : W2n[k * 64 + (c - 64)];
        W2T[idx] = f2bf(v);
    }
    __syncthreads();
    int e0 = blockIdx.x * TILE;
    #pragma unroll
    for (int j = 0; j < 16; ++j) {
        int e = e0 + tid + j * 256;
        if (e < N_EDGES) atomicAdd(&cnt[dst[e] >> BSH], 1);
    }
    __syncthreads();
    for (int i = tid; i < NBUK; i += 256)
        if (cnt[i]) atomicAdd(&bukcnt[i], cnt[i]);
}

// ---------------- bucket scan ----------------
__global__ __launch_bounds__(256) void k_bukscan(const int* __restrict__ bukcnt,
                                                 int* __restrict__ bukoff,
                                                 int* __restrict__ bukcur) {
    __shared__ int sh[256];
    int t = threadIdx.x;
    int v = (t < NBUK) ? bukcnt[t] : 0;
    sh[t] = v;
    __syncthreads();
    for (int o = 1; o < 256; o <<= 1) {
        int a = sh[t];
        int ap = (t >= o) ? sh[t - o] : 0;
        __syncthreads();
        sh[t] = a + ap;
        __syncthreads();
    }
    if (t < NBUK) { bukoff[t] = sh[t] - v; bukcur[t] = 0; }
    if (t == 255) bukoff[NBUK] = sh[NBUK - 1];
}

// ---------------- multisplit partition ----------------
__global__ __launch_bounds__(256) void k_part(const int* __restrict__ src,
                                              const int* __restrict__ dst,
                                              const int* __restrict__ bukoff,
                                              int* __restrict__ bukcur,
                                              unsigned int* __restrict__ pairbuf) {
    __shared__ int cnt[NBUK];
    __shared__ int sbase[NBUK];
    __shared__ int gbase[NBUK];
    __shared__ int stmp[256];
    __shared__ unsigned int buf[TILE];
    __shared__ unsigned short bid[TILE];
    int tid = threadIdx.x;
    int e0 = blockIdx.x * TILE;
    int n = min(TILE, N_EDGES - e0);

    for (int i = tid; i < NBUK; i += 256) cnt[i] = 0;
    __syncthreads();

    int myb[16];
    int mypos[16];
    unsigned int myv[16];
    #pragma unroll
    for (int j = 0; j < 16; ++j) {
        int idx = tid + j * 256;
        myb[j] = -1;
        if (idx < n) {
            int s = src[e0 + idx];
            int d = dst[e0 + idx];
            int b = d >> BSH;
            myb[j] = b;
            myv[j] = ((unsigned int)(d & (BUKN - 1)) << 17) | (unsigned int)s;
            mypos[j] = atomicAdd(&cnt[b], 1);
        }
    }
    __syncthreads();

    int v = (tid < NBUK) ? cnt[tid] : 0;
    stmp[tid] = v;
    __syncthreads();
    for (int o = 1; o < 256; o <<= 1) {
        int a = stmp[tid];
        int ap = (tid >= o) ? stmp[tid - o] : 0;
        __syncthreads();
        stmp[tid] = a + ap;
        __syncthreads();
    }
    if (tid < NBUK) {
        sbase[tid] = stmp[tid] - v;
        gbase[tid] = atomicAdd(&bukcur[tid], v);
    }
    __syncthreads();

    #pragma unroll
    for (int j = 0; j < 16; ++j) {
        if (myb[j] >= 0) {
            int slot = sbase[myb[j]] + mypos[j];
            buf[slot] = myv[j];
            bid[slot] = (unsigned short)myb[j];
        }
    }
    __syncthreads();

    for (int slot = tid; slot < n; slot += 256) {
        int b = bid[slot];
        pairbuf[bukoff[b] + gbase[b] + (slot - sbase[b])] = buf[slot];
    }
}

// ---------------- per-bucket degree histogram ----------------
__global__ __launch_bounds__(256) void k_bdeg(const int* __restrict__ bukoff,
                                              const unsigned int* __restrict__ pairbuf,
                                              int* __restrict__ degi) {
    __shared__ int deg[BUKN];
    int tid = threadIdx.x;
    int b = blockIdx.x;
    int n0 = b << BSH;
    for (int i = tid; i < BUKN; i += 256) deg[i] = 0;
    __syncthreads();
    int lo = bukoff[b], hi = bukoff[b + 1];
    for (int i = lo + tid; i < hi; i += 256)
        atomicAdd(&deg[pairbuf[i] >> 17], 1);
    __syncthreads();
    for (int i = tid; i < BUKN; i += 256) {
        int node = n0 + i;
        if (node < N_NODES) degi[node] = deg[i];
    }
}

// ---------------- device-wide scan of degi ----------------

__global__ void k_psum(const int* __restrict__ degi, int* __restrict__ bsum) {
    __shared__ int red[256];
    int b0 = blockIdx.x * CH;
    int e = min(b0 + CH, N_NODES);
    int s = 0;
    for (int i = b0 + threadIdx.x; i < e; i += 256) s += degi[i];
    red[threadIdx.x] = s;
    __syncthreads();
    for (int o = 128; o > 0; o >>= 1) {
        if (threadIdx.x < o) red[threadIdx.x] += red[threadIdx.x + o];
        __syncthreads();
    }
    if (threadIdx.x == 0) bsum[blockIdx.x] = red[0];
}

__global__ void k_bscan(const int* __restrict__ bsum, int* __restrict__ boff,
                        int* __restrict__ row_start) {
    __shared__ int sh[NB];
    int t = threadIdx.x;
    sh[t] = bsum[t];
    __syncthreads();
    for (int o = 1; o < NB; o <<= 1) {
        int v = sh[t];
        int vp = (t >= o) ? sh[t - o] : 0;
        __syncthreads();
        sh[t] = v + vp;
        __syncthreads();
    }
    boff[t] = (t > 0) ? sh[t - 1] : 0;
    if (t == NB - 1) row_start[N_NODES] = sh[NB - 1];
}

__global__ void k_apply(const int* __restrict__ degi, const int* __restrict__ boff,
                        int* __restrict__ row_start, float* __restrict__ invd) {
    __shared__ int sh[256];
    int b0 = blockIdx.x * CH;
    int e = min(b0 + CH, N_NODES);
    int carry = boff[blockIdx.x];
    for (int base = b0; base < e; base += 256) {
        int i = base + threadIdx.x;
        int v = (i < e) ? degi[i] : 0;
        sh[threadIdx.x] = v;
        __syncthreads();
        for (int o = 1; o < 256; o <<= 1) {
            int a = sh[threadIdx.x];
            int ap = (threadIdx.x >= o) ? sh[threadIdx.x - o] : 0;
            __syncthreads();
            sh[threadIdx.x] = a + ap;
            __syncthreads();
        }
        int incl = sh[threadIdx.x];
        int excl = incl - v;
        if (i < e) {
            row_start[i] = carry + excl;
            invd[i] = 1.0f / fmaxf((float)v, 1.0f);
        }
        int total = sh[255];
        __syncthreads();
        carry += total;
    }
}

// ---------------- per-bucket fine scatter ----------------
__global__ __launch_bounds__(256) void k_fine(const int* __restrict__ bukoff,
                                              const unsigned int* __restrict__ pairbuf,
                                              const int* __restrict__ row_start,
                                              int* __restrict__ csr_src) {
    __shared__ int cur[BUKN];
    int tid = threadIdx.x;
    int b = blockIdx.x;
    int n0 = b << BSH;
    for (int i = tid; i < BUKN; i += 256) {
        int node = n0 + i;
        cur[i] = (node < N_NODES) ? row_start[node] : 0;
    }
    __syncthreads();
    int lo = bukoff[b], hi = bukoff[b + 1];
    for (int i = lo + tid; i < hi; i += 256) {
        unsigned int v = pairbuf[i];
        int dl = v >> 17;
        int s = (int)(v & 0x1FFFF);
        int ofs = atomicAdd(&cur[dl], 1);
        csr_src[ofs] = s;
    }
}

// ---------------- layer-1 neighbor mean ----------------

__global__ void k_agg1(const int* __restrict__ row_start, const int* __restrict__ csr_src,
                       const float4* __restrict__ x4, const float* __restrict__ invd,
                       float4* __restrict__ hn4) {
    int wid = (blockIdx.x * blockDim.x + threadIdx.x) >> 6;
    int lane = threadIdx.x & 63;
    int n = wid * 16 + (lane >> 2);
    if (n >= N_NODES) return;
    int sub = lane & 3;
    int b = row_start[n], e = row_start[n + 1];
    float s0 = 0.f, s1 = 0.f, s2 = 0.f;
    for (int i = b + sub; i < e; i += 4) {
        float4 v = x4[csr_src[i]];
        s0 += v.x; s1 += v.y; s2 += v.z;
    }
    s0 += __shfl_xor(s0, 1, 64); s0 += __shfl_xor(s0, 2, 64);
    s1 += __shfl_xor(s1, 1, 64); s1 += __shfl_xor(s1, 2, 64);
    s2 += __shfl_xor(s2, 1, 64); s2 += __shfl_xor(s2, 2, 64);
    if (sub == 0) {
        float id = invd[n];
        hn4[n] = make_float4(s0 * id, s1 * id, s2 * id, 0.0f);
    }
}

// ---------------- fused layer1 + layer2 GEMM via bf16 MFMA ----------------
// self half (cols 0-63) -> out fp32 (+b2); neigh half (cols 64-127) -> pbf (bf16)
#define SHK 168
__global__ __launch_bounds__(256, 4) void k_gemm(
        const float4* __restrict__ x4, const float4* __restrict__ hn4,
        const float* __restrict__ W1t,
        const unsigned short* __restrict__ W2T,
        const float* __restrict__ b2,
        float* __restrict__ out, unsigned short* __restrict__ pbf) {
    __shared__ unsigned short shA[64 * SHK];   // 21.5 KB
    const int n0 = blockIdx.x * 64;
    const int tid = threadIdx.x;

    {
        int n = tid & 63;
        int node = n0 + n;
        int kbase = 2 * (tid >> 6);
        float4 xs = make_float4(0.f, 0.f, 0.f, 0.f);
        float4 xn = make_float4(0.f, 0.f, 0.f, 0.f);
        if (node < N_NODES) { xs = x4[node]; xn = hn4[node]; }
        #pragma unroll 4
        for (int j = 0; j < 20; ++j) {
            int k = kbase + 8 * j;
            float4 wa0 = *(const float4*)&W1t[k * 8 + 0];
            float4 wb0 = *(const float4*)&W1t[k * 8 + 4];
            float4 wa1 = *(const float4*)&W1t[(k + 1) * 8 + 0];
            float4 wb1 = *(const float4*)&W1t[(k + 1) * 8 + 4];
            float h0 = wa0.w + xs.x * wa0.x + xs.y * wa0.y + xs.z * wa0.z
                             + xn.x * wb0.x + xn.y * wb0.y + xn.z * wb0.z;
            float h1 = wa1.w + xs.x * wa1.x + xs.y * wa1.y + xs.z * wa1.z
                             + xn.x * wb1.x + xn.y * wb1.y + xn.z * wb1.z;
            h0 = fmaxf(h0, 0.0f);
            h1 = fmaxf(h1, 0.0f);
            unsigned int pk = (unsigned int)f2bf(h0) | ((unsigned int)f2bf(h1) << 16);
            *(unsigned int*)&shA[n * SHK + k] = pk;
        }
    }
    __syncthreads();

    const int lane = tid & 63;
    const int w = tid >> 6;
    const int c16 = lane & 15;
    const int quad = lane >> 4;
    const int ko = quad * 8;

    f32x4 acc[8];
    #pragma unroll
    for (int t = 0; t < 8; ++t) acc[t] = (f32x4){0.f, 0.f, 0.f, 0.f};

    #pragma unroll
    for (int ks = 0; ks < 5; ++ks) {
        int k0 = ks * 32;
        bf16x8 a = *(const bf16x8*)&shA[(w * 16 + c16) * SHK + k0 + ko];
        #pragma unroll
        for (int t = 0; t < 8; ++t) {
            bf16x8 b = *(const bf16x8*)&W2T[(t * 16 + c16) * KPAD + k0 + ko];
            acc[t] = __builtin_amdgcn_mfma_f32_16x16x32_bf16(a, b, acc[t], 0, 0, 0);
        }
    }

    const int rbase = n0 + w * 16 + quad * 4;
    #pragma unroll
    for (int t = 0; t < 4; ++t) {
        int gc = t * 16 + c16;
        float badd = b2[gc];
        #pragma unroll
        for (int i = 0; i < 4; ++i) {
            int node = rbase + i;
            if (node < N_NODES) out[(size_t)node * OUTF + gc] = acc[t][i] + badd;
        }
    }
    #pragma unroll
    for (int t = 4; t < 8; ++t) {
        int cc = t * 16 + c16 - 64;
        #pragma unroll
        for (int i = 0; i < 4; ++i) {
            int node = rbase + i;
            if (node < N_NODES) pbf[(size_t)node * OUTF + cc] = f2bf(acc[t][i]);
        }
    }
}

// ---------------- layer-2 pull: 1 wave/node, 8 rows per issue, bf16 p ----------------
// lane = (g = lane>>3: edge group, c = lane&7: col chunk of 8)
__global__ void k_pull(const int* __restrict__ row_start, const int* __restrict__ csr_src,
                       const unsigned short* __restrict__ pbf, const float* __restrict__ invd,
                       float* __restrict__ out) {
    int n = blockIdx.x * 4 + (threadIdx.x >> 6);
    if (n >= N_NODES) return;
    int lane = threadIdx.x & 63;
    int g = lane >> 3;
    int c = lane & 7;
    int b = row_start[n], e = row_start[n + 1];
    float acc[8];
    #pragma unroll
    for (int q = 0; q < 8; ++q) acc[q] = 0.0f;
    for (int i = b + g; i < e; i += 8) {
        int s = csr_src[i];
        bf16x8 v = *(const bf16x8*)&pbf[(size_t)s * OUTF + c * 8];
        #pragma unroll
        for (int q = 0; q < 8; ++q) acc[q] += bf2f((unsigned short)v[q]);
    }
    #pragma unroll
    for (int q = 0; q < 8; ++q) {
        acc[q] += __shfl_xor(acc[q], 8, 64);
        acc[q] += __shfl_xor(acc[q], 16, 64);
        acc[q] += __shfl_xor(acc[q], 32, 64);
    }
    if (g == 0) {
        float id = invd[n];
        float4 o0 = *(const float4*)&out[(size_t)n * OUTF + c * 8];
        float4 o1 = *(const float4*)&out[(size_t)n * OUTF + c * 8 + 4];
        o0.x += acc[0] * id; o0.y += acc[1] * id;
        o0.z += acc[2] * id; o0.w += acc[3] * id;
        o1.x += acc[4] * id; o1.y += acc[5] * id;
        o1.z += acc[6] * id; o1.w += acc[7] * id;
        *(float4*)&out[(size_t)n * OUTF + c * 8]     = o0;
        *(float4*)&out[(size_t)n * OUTF + c * 8 + 4] = o1;
    }
}

// ---------------- launcher ----------------

static inline size_t al256(size_t v) { return (v + 255) & ~(size_t)255; }

extern "C" void kernel_launch(void* const* d_in, const int* in_sizes, int n_in,
                              void* d_out, int out_size, void* d_ws, size_t ws_size,
                              hipStream_t stream) {
    const float* x   = (const float*)d_in[0];
    const int*   src = (const int*)d_in[1];
    const int*   dst = (const int*)d_in[2];
    const float* W1s = (const float*)d_in[3];
    const float* W1n = (const float*)d_in[4];
    const float* b1  = (const float*)d_in[5];
    const float* W2s = (const float*)d_in[6];
    const float* W2n = (const float*)d_in[7];
    const float* b2  = (const float*)d_in[8];
    float* out = (float*)d_out;

    char* ws = (char*)d_ws;
    size_t off = 0;
    int*   degi      = (int*)(ws + off); off += al256((size_t)N_NODES * 4);
    int*   row_start = (int*)(ws + off); off += al256((size_t)(N_NODES + 1) * 4);
    int*   csr_src   = (int*)(ws + off); off += al256((size_t)N_EDGES * 4);
    float* invd      = (float*)(ws + off); off += al256((size_t)N_NODES * 4);
    unsigned short* pbf = (unsigned short*)(ws + off); off += al256((size_t)N_NODES * OUTF * 2);
    int*   bsum      = (int*)(ws + off); off += al256((size_t)NB * 4);
    int*   boff      = (int*)(ws + off); off += al256((size_t)NB * 4);
    float4* x4       = (float4*)(ws + off); off += al256((size_t)N_NODES * 16);
    float4* hn4      = (float4*)(ws + off); off += al256((size_t)N_NODES * 16);
    unsigned int* pairbuf = (unsigned int*)(ws + off); off += al256((size_t)N_EDGES * 4);
    int*   bukcnt    = (int*)(ws + off); off += al256((size_t)NBUK * 4);
    int*   bukoff    = (int*)(ws + off); off += al256((size_t)(NBUK + 1) * 4);
    int*   bukcur    = (int*)(ws + off); off += al256((size_t)NBUK * 4);
    float* W1t       = (float*)(ws + off); off += al256((size_t)KPAD * 8 * 4);
    unsigned short* W2T = (unsigned short*)(ws + off); off += al256((size_t)128 * KPAD * 2);

    hipMemsetAsync(bukcnt, 0, (size_t)NBUK * 4, stream);

    k_prep<<<NTILE, 256, 0, stream>>>(x, x4, dst, bukcnt, W1s, W1n, b1, W2s, W2n, W1t, W2T);
    k_bukscan<<<1, 256, 0, stream>>>(bukcnt, bukoff, bukcur);
    k_part<<<NTILE, 256, 0, stream>>>(src, dst, bukoff, bukcur, pairbuf);
    k_bdeg<<<NBUK, 256, 0, stream>>>(bukoff, pairbuf, degi);
    k_psum<<<NB, 256, 0, stream>>>(degi, bsum);
    k_bscan<<<1, NB, 0, stream>>>(bsum, boff, row_start);
    k_apply<<<NB, 256, 0, stream>>>(degi, boff, row_start, invd);
    k_fine<<<NBUK, 256, 0, stream>>>(bukoff, pairbuf, row_start, csr_src);
    {   // layer-1 neighbor mean
        int waves = (N_NODES + 15) / 16;
        int blocks = (waves * 64 + 255) / 256;
        k_agg1<<<blocks, 256, 0, stream>>>(row_start, csr_src, x4, invd, hn4);
    }
    {   // fused layer1+layer2 GEMM (bf16 MFMA)
        int blocks = (N_NODES + 63) / 64;
        k_gemm<<<blocks, 256, 0, stream>>>(x4, hn4, W1t, W2T, b2, out, pbf);
    }
    {   // layer-2 neighbor aggregation (pull, bf16)
        int blocks = (N_NODES + 3) / 4;
        k_pull<<<blocks, 256, 0, stream>>>(row_start, csr_src, pbf, invd, out);
    }
}

// Round 9
// 162.231 us; speedup vs baseline: 5.7083x; 1.0621x over previous
//
#include <hip/hip_runtime.h>

#define N_NODES 100000
#define N_EDGES 1600000
#define HID 150
#define KPAD 160
#define OUTF 64
#define BSH 9                          // 512 nodes per bucket
#define BUKN 512                       // nodes per bucket
#define NBUK ((N_NODES + BUKN - 1) / BUKN)   // 196 buckets
#define TILE 4096                      // edges per partition tile
#define NTILE ((N_EDGES + TILE - 1) / TILE)  // 391 tiles

typedef short bf16x8 __attribute__((ext_vector_type(8)));
typedef float f32x4 __attribute__((ext_vector_type(4)));

__device__ __forceinline__ unsigned short f2bf(float f) {
    union { float f; unsigned u; } v; v.f = f;
    unsigned r = (v.u + 0x7FFFu + ((v.u >> 16) & 1u)) >> 16;
    return (unsigned short)r;
}

__device__ __forceinline__ float bf2f(unsigned short b) {
    union { unsigned u; float f; } v;
    v.u = ((unsigned)b) << 16;
    return v.f;
}

// ---------------- prep: pad x -> x4, bucket histogram of dst, W1t/W2T pack ----------------
__global__ __launch_bounds__(256) void k_prep(const float* __restrict__ x,
                                              float4* __restrict__ x4,
                                              const int* __restrict__ dst,
                                              int* __restrict__ bukcnt,
                                              const float* __restrict__ W1s,
                                              const float* __restrict__ W1n,
                                              const float* __restrict__ b1,
                                              const float* __restrict__ W2s,
                                              const float* __restrict__ W2n,
                                              float* __restrict__ W1t,
                                              unsigned short* __restrict__ W2T) {
    __shared__ int cnt[NBUK];
    int tid = threadIdx.x;
    for (int i = tid; i < NBUK; i += 256) cnt[i] = 0;
    int idx = blockIdx.x * 256 + tid;
    if (idx < N_NODES)
        x4[idx] = make_float4(x[idx * 3 + 0], x[idx * 3 + 1], x[idx * 3 + 2], 0.0f);
    if (idx < KPAD) {
        int k = idx;
        bool ok = (k < HID);
        W1t[k * 8 + 0] = ok ? W1s[0 * HID + k] : 0.0f;
        W1t[k * 8 + 1] = ok ? W1s[1 * HID + k] : 0.0f;
        W1t[k * 8 + 2] = ok ? W1s[2 * HID + k] : 0.0f;
        W1t[k * 8 + 3] = ok ? b1[k] : 0.0f;
        W1t[k * 8 + 4] = ok ? W1n[0 * HID + k] : 0.0f;
        W1t[k * 8 + 5] = ok ? W1n[1 * HID + k] : 0.0f;
        W1t[k * 8 + 6] = ok ? W1n[2 * HID + k] : 0.0f;
        W1t[k * 8 + 7] = 0.0f;
    }
    if (idx < 128 * KPAD) {
        int c = idx / KPAD, k = idx - c * KPAD;
        float v = 0.0f;
        if (k < HID) v = (c < 64) ? W2s[k * 64 + c] : W2n[k * 64 + (c - 64)];
        W2T[idx] = f2bf(v);
    }
    __syncthreads();
    int e0 = blockIdx.x * TILE;
    #pragma unroll
    for (int j = 0; j < 16; ++j) {
        int e = e0 + tid + j * 256;
        if (e < N_EDGES) atomicAdd(&cnt[dst[e] >> BSH], 1);
    }
    __syncthreads();
    for (int i = tid; i < NBUK; i += 256)
        if (cnt[i]) atomicAdd(&bukcnt[i], cnt[i]);
}

// ---------------- bucket scan: bukcnt -> bukoff (exclusive), zero bukcur ----------------
__global__ __launch_bounds__(256) void k_bukscan(const int* __restrict__ bukcnt,
                                                 int* __restrict__ bukoff,
                                                 int* __restrict__ bukcur,
                                                 int* __restrict__ row_start) {
    __shared__ int sh[256];
    int t = threadIdx.x;
    int v = (t < NBUK) ? bukcnt[t] : 0;
    sh[t] = v;
    __syncthreads();
    for (int o = 1; o < 256; o <<= 1) {
        int a = sh[t];
        int ap = (t >= o) ? sh[t - o] : 0;
        __syncthreads();
        sh[t] = a + ap;
        __syncthreads();
    }
    if (t < NBUK) { bukoff[t] = sh[t] - v; bukcur[t] = 0; }
    if (t == 255) {
        bukoff[NBUK] = sh[NBUK - 1];
        row_start[N_NODES] = sh[NBUK - 1];
    }
}

// ---------------- multisplit partition ----------------
__global__ __launch_bounds__(256) void k_part(const int* __restrict__ src,
                                              const int* __restrict__ dst,
                                              const int* __restrict__ bukoff,
                                              int* __restrict__ bukcur,
                                              unsigned int* __restrict__ pairbuf) {
    __shared__ int cnt[NBUK];
    __shared__ int sbase[NBUK];
    __shared__ int gbase[NBUK];
    __shared__ int stmp[256];
    __shared__ unsigned int buf[TILE];
    __shared__ unsigned short bid[TILE];
    int tid = threadIdx.x;
    int e0 = blockIdx.x * TILE;
    int n = min(TILE, N_EDGES - e0);

    for (int i = tid; i < NBUK; i += 256) cnt[i] = 0;
    __syncthreads();

    int myb[16];
    int mypos[16];
    unsigned int myv[16];
    #pragma unroll
    for (int j = 0; j < 16; ++j) {
        int idx = tid + j * 256;
        myb[j] = -1;
        if (idx < n) {
            int s = src[e0 + idx];
            int d = dst[e0 + idx];
            int b = d >> BSH;
            myb[j] = b;
            myv[j] = ((unsigned int)(d & (BUKN - 1)) << 17) | (unsigned int)s;
            mypos[j] = atomicAdd(&cnt[b], 1);
        }
    }
    __syncthreads();

    int v = (tid < NBUK) ? cnt[tid] : 0;
    stmp[tid] = v;
    __syncthreads();
    for (int o = 1; o < 256; o <<= 1) {
        int a = stmp[tid];
        int ap = (tid >= o) ? stmp[tid - o] : 0;
        __syncthreads();
        stmp[tid] = a + ap;
        __syncthreads();
    }
    if (tid < NBUK) {
        sbase[tid] = stmp[tid] - v;
        gbase[tid] = atomicAdd(&bukcur[tid], v);
    }
    __syncthreads();

    #pragma unroll
    for (int j = 0; j < 16; ++j) {
        if (myb[j] >= 0) {
            int slot = sbase[myb[j]] + mypos[j];
            buf[slot] = myv[j];
            bid[slot] = (unsigned short)myb[j];
        }
    }
    __syncthreads();

    for (int slot = tid; slot < n; slot += 256) {
        int b = bid[slot];
        pairbuf[bukoff[b] + gbase[b] + (slot - sbase[b])] = buf[slot];
    }
}

// ---------------- merged per-bucket CSR finish: hist + scan + row_start/invd + scatter --
__global__ __launch_bounds__(256) void k_fine(const int* __restrict__ bukoff,
                                              const unsigned int* __restrict__ pairbuf,
                                              int* __restrict__ row_start,
                                              float* __restrict__ invd,
                                              int* __restrict__ csr_src) {
    __shared__ int deg[BUKN];      // counts, later reused as scatter cursors
    __shared__ int scan[256];
    int tid = threadIdx.x;
    int b = blockIdx.x;
    int n0 = b << BSH;
    int lo = bukoff[b], hi = bukoff[b + 1];

    for (int i = tid; i < BUKN; i += 256) deg[i] = 0;
    __syncthreads();
    for (int i = lo + tid; i < hi; i += 256)
        atomicAdd(&deg[pairbuf[i] >> 17], 1);
    __syncthreads();

    // 512-wide exclusive scan: thread t owns elements 2t, 2t+1
    int d0 = deg[2 * tid], d1 = deg[2 * tid + 1];
    int pairsum = d0 + d1;
    scan[tid] = pairsum;
    __syncthreads();
    for (int o = 1; o < 256; o <<= 1) {
        int a = scan[tid];
        int ap = (tid >= o) ? scan[tid - o] : 0;
        __syncthreads();
        scan[tid] = a + ap;
        __syncthreads();
    }
    int r0 = lo + scan[tid] - pairsum;
    int r1 = r0 + d0;
    int node0 = n0 + 2 * tid, node1 = node0 + 1;
    if (node0 < N_NODES) { row_start[node0] = r0; invd[node0] = 1.0f / fmaxf((float)d0, 1.0f); }
    if (node1 < N_NODES) { row_start[node1] = r1; invd[node1] = 1.0f / fmaxf((float)d1, 1.0f); }
    __syncthreads();
    // reuse deg[] as cursors
    deg[2 * tid] = r0;
    deg[2 * tid + 1] = r1;
    __syncthreads();
    for (int i = lo + tid; i < hi; i += 256) {
        unsigned int v = pairbuf[i];
        int dl = v >> 17;
        int ofs = atomicAdd(&deg[dl], 1);
        csr_src[ofs] = (int)(v & 0x1FFFF);
    }
}

// ---------------- layer-1 neighbor mean ----------------

__global__ void k_agg1(const int* __restrict__ row_start, const int* __restrict__ csr_src,
                       const float4* __restrict__ x4, const float* __restrict__ invd,
                       float4* __restrict__ hn4) {
    int wid = (blockIdx.x * blockDim.x + threadIdx.x) >> 6;
    int lane = threadIdx.x & 63;
    int n = wid * 16 + (lane >> 2);
    if (n >= N_NODES) return;
    int sub = lane & 3;
    int b = row_start[n], e = row_start[n + 1];
    float s0 = 0.f, s1 = 0.f, s2 = 0.f;
    for (int i = b + sub; i < e; i += 4) {
        float4 v = x4[csr_src[i]];
        s0 += v.x; s1 += v.y; s2 += v.z;
    }
    s0 += __shfl_xor(s0, 1, 64); s0 += __shfl_xor(s0, 2, 64);
    s1 += __shfl_xor(s1, 1, 64); s1 += __shfl_xor(s1, 2, 64);
    s2 += __shfl_xor(s2, 1, 64); s2 += __shfl_xor(s2, 2, 64);
    if (sub == 0) {
        float id = invd[n];
        hn4[n] = make_float4(s0 * id, s1 * id, s2 * id, 0.0f);
    }
}

// ---------------- fused layer1 + layer2 GEMM via bf16 MFMA ----------------
// Writes one bf16 row per node: ob[node][0..63] = self+b2, ob[node][64..127] = p
#define SHK 168
__global__ __launch_bounds__(256, 4) void k_gemm(
        const float4* __restrict__ x4, const float4* __restrict__ hn4,
        const float* __restrict__ W1t,
        const unsigned short* __restrict__ W2T,
        const float* __restrict__ b2,
        unsigned short* __restrict__ ob) {
    __shared__ unsigned short shA[64 * SHK];   // 21.5 KB
    const int n0 = blockIdx.x * 64;
    const int tid = threadIdx.x;

    {
        int n = tid & 63;
        int node = n0 + n;
        int kbase = 2 * (tid >> 6);
        float4 xs = make_float4(0.f, 0.f, 0.f, 0.f);
        float4 xn = make_float4(0.f, 0.f, 0.f, 0.f);
        if (node < N_NODES) { xs = x4[node]; xn = hn4[node]; }
        #pragma unroll 4
        for (int j = 0; j < 20; ++j) {
            int k = kbase + 8 * j;
            float4 wa0 = *(const float4*)&W1t[k * 8 + 0];
            float4 wb0 = *(const float4*)&W1t[k * 8 + 4];
            float4 wa1 = *(const float4*)&W1t[(k + 1) * 8 + 0];
            float4 wb1 = *(const float4*)&W1t[(k + 1) * 8 + 4];
            float h0 = wa0.w + xs.x * wa0.x + xs.y * wa0.y + xs.z * wa0.z
                             + xn.x * wb0.x + xn.y * wb0.y + xn.z * wb0.z;
            float h1 = wa1.w + xs.x * wa1.x + xs.y * wa1.y + xs.z * wa1.z
                             + xn.x * wb1.x + xn.y * wb1.y + xn.z * wb1.z;
            h0 = fmaxf(h0, 0.0f);
            h1 = fmaxf(h1, 0.0f);
            unsigned int pk = (unsigned int)f2bf(h0) | ((unsigned int)f2bf(h1) << 16);
            *(unsigned int*)&shA[n * SHK + k] = pk;
        }
    }
    __syncthreads();

    const int lane = tid & 63;
    const int w = tid >> 6;
    const int c16 = lane & 15;
    const int quad = lane >> 4;
    const int ko = quad * 8;

    f32x4 acc[8];
    #pragma unroll
    for (int t = 0; t < 8; ++t) acc[t] = (f32x4){0.f, 0.f, 0.f, 0.f};

    #pragma unroll
    for (int ks = 0; ks < 5; ++ks) {
        int k0 = ks * 32;
        bf16x8 a = *(const bf16x8*)&shA[(w * 16 + c16) * SHK + k0 + ko];
        #pragma unroll
        for (int t = 0; t < 8; ++t) {
            bf16x8 b = *(const bf16x8*)&W2T[(t * 16 + c16) * KPAD + k0 + ko];
            acc[t] = __builtin_amdgcn_mfma_f32_16x16x32_bf16(a, b, acc[t], 0, 0, 0);
        }
    }

    const int rbase = n0 + w * 16 + quad * 4;
    #pragma unroll
    for (int t = 0; t < 8; ++t) {
        int cc = t * 16 + c16;
        float badd = (t < 4) ? b2[cc] : 0.0f;
        #pragma unroll
        for (int i = 0; i < 4; ++i) {
            int node = rbase + i;
            if (node < N_NODES) ob[(size_t)node * 128 + cc] = f2bf(acc[t][i] + badd);
        }
    }
}

// ---------------- layer-2 pull: gather p half of ob, add self half, pure store ----------
__global__ void k_pull(const int* __restrict__ row_start, const int* __restrict__ csr_src,
                       const unsigned short* __restrict__ ob, const float* __restrict__ invd,
                       float* __restrict__ out) {
    int n = blockIdx.x * 4 + (threadIdx.x >> 6);
    if (n >= N_NODES) return;
    int lane = threadIdx.x & 63;
    int g = lane >> 3;
    int c = lane & 7;
    int b = row_start[n], e = row_start[n + 1];
    float acc[8];
    #pragma unroll
    for (int q = 0; q < 8; ++q) acc[q] = 0.0f;
    for (int i = b + g; i < e; i += 8) {
        int s = csr_src[i];
        bf16x8 v = *(const bf16x8*)&ob[(size_t)s * 128 + 64 + c * 8];
        #pragma unroll
        for (int q = 0; q < 8; ++q) acc[q] += bf2f((unsigned short)v[q]);
    }
    #pragma unroll
    for (int q = 0; q < 8; ++q) {
        acc[q] += __shfl_xor(acc[q], 8, 64);
        acc[q] += __shfl_xor(acc[q], 16, 64);
        acc[q] += __shfl_xor(acc[q], 32, 64);
    }
    if (g == 0) {
        float id = invd[n];
        bf16x8 sv = *(const bf16x8*)&ob[(size_t)n * 128 + c * 8];
        float4 o0, o1;
        o0.x = bf2f((unsigned short)sv[0]) + acc[0] * id;
        o0.y = bf2f((unsigned short)sv[1]) + acc[1] * id;
        o0.z = bf2f((unsigned short)sv[2]) + acc[2] * id;
        o0.w = bf2f((unsigned short)sv[3]) + acc[3] * id;
        o1.x = bf2f((unsigned short)sv[4]) + acc[4] * id;
        o1.y = bf2f((unsigned short)sv[5]) + acc[5] * id;
        o1.z = bf2f((unsigned short)sv[6]) + acc[6] * id;
        o1.w = bf2f((unsigned short)sv[7]) + acc[7] * id;
        *(float4*)&out[(size_t)n * OUTF + c * 8]     = o0;
        *(float4*)&out[(size_t)n * OUTF + c * 8 + 4] = o1;
    }
}

// ---------------- launcher ----------------

static inline size_t al256(size_t v) { return (v + 255) & ~(size_t)255; }

extern "C" void kernel_launch(void* const* d_in, const int* in_sizes, int n_in,
                              void* d_out, int out_size, void* d_ws, size_t ws_size,
                              hipStream_t stream) {
    const float* x   = (const float*)d_in[0];
    const int*   src = (const int*)d_in[1];
    const int*   dst = (const int*)d_in[2];
    const float* W1s = (const float*)d_in[3];
    const float* W1n = (const float*)d_in[4];
    const float* b1  = (const float*)d_in[5];
    const float* W2s = (const float*)d_in[6];
    const float* W2n = (const float*)d_in[7];
    const float* b2  = (const float*)d_in[8];
    float* out = (float*)d_out;

    char* ws = (char*)d_ws;
    size_t off = 0;
    int*   row_start = (int*)(ws + off); off += al256((size_t)(N_NODES + 1) * 4);
    int*   csr_src   = (int*)(ws + off); off += al256((size_t)N_EDGES * 4);
    float* invd      = (float*)(ws + off); off += al256((size_t)N_NODES * 4);
    unsigned short* ob = (unsigned short*)(ws + off); off += al256((size_t)N_NODES * 128 * 2);
    float4* x4       = (float4*)(ws + off); off += al256((size_t)N_NODES * 16);
    float4* hn4      = (float4*)(ws + off); off += al256((size_t)N_NODES * 16);
    unsigned int* pairbuf = (unsigned int*)(ws + off); off += al256((size_t)N_EDGES * 4);
    int*   bukcnt    = (int*)(ws + off); off += al256((size_t)NBUK * 4);
    int*   bukoff    = (int*)(ws + off); off += al256((size_t)(NBUK + 1) * 4);
    int*   bukcur    = (int*)(ws + off); off += al256((size_t)NBUK * 4);
    float* W1t       = (float*)(ws + off); off += al256((size_t)KPAD * 8 * 4);
    unsigned short* W2T = (unsigned short*)(ws + off); off += al256((size_t)128 * KPAD * 2);

    hipMemsetAsync(bukcnt, 0, (size_t)NBUK * 4, stream);

    k_prep<<<NTILE, 256, 0, stream>>>(x, x4, dst, bukcnt, W1s, W1n, b1, W2s, W2n, W1t, W2T);
    k_bukscan<<<1, 256, 0, stream>>>(bukcnt, bukoff, bukcur, row_start);
    k_part<<<NTILE, 256, 0, stream>>>(src, dst, bukoff, bukcur, pairbuf);
    // merged: hist + scan + row_start/invd + scatter
    k_fine<<<NBUK, 256, 0, stream>>>(bukoff, pairbuf, row_start, invd, csr_src);
    {   // layer-1 neighbor mean
        int waves = (N_NODES + 15) / 16;
        int blocks = (waves * 64 + 255) / 256;
        k_agg1<<<blocks, 256, 0, stream>>>(row_start, csr_src, x4, invd, hn4);
    }
    {   // fused layer1+layer2 GEMM (bf16 MFMA) -> unified bf16 row buffer
        int blocks = (N_NODES + 63) / 64;
        k_gemm<<<blocks, 256, 0, stream>>>(x4, hn4, W1t, W2T, b2, ob);
    }
    {   // layer-2 neighbor aggregation (pull, pure store)
        int blocks = (N_NODES + 3) / 4;
        k_pull<<<blocks, 256, 0, stream>>>(row_start, csr_src, ob, invd, out);
    }
}